// Round 15
// baseline (278.114 us; speedup 1.0000x reference)
//
#include <hip/hip_runtime.h>
#include <hip/hip_fp16.h>

// ---------------------------------------------------------------------------
// GCN forward on MI355X — round 15.
//  * NBLK 256->1024: bin_count/fill were 1 block/CU (4 waves, 12.5% occ) —
//    the LDS-cursor design had pinned grid size.  Now 4 blocks/CU.
//  * g0h = dinv * fp16(table[x]) materialized in build_csr (coalesced):
//    layer1's gather becomes single-load (was xd[s] -> th4[x_s] dependent
//    chain + convert + hfma); now identical in structure to layer2.
//  * Layers back to __launch_bounds__(256,8); unroll x2 kept (neutral).
// ---------------------------------------------------------------------------

#define DD 64          // feature dim
#define BKT 256        // nodes per bucket (CSR build)
#define MAXK 1024      // max buckets; hist/cur row stride
#define NBLK 1024      // partition blocks (chunks)
#define SLACK 772      // per-bucket csr slack: 3*256 pad + 4 alignment

typedef _Float16 half8_t __attribute__((ext_vector_type(8)));
typedef float float4_t __attribute__((ext_vector_type(4)));
union F4H8 { float4 f; half8_t h; };
union H8   { float4 f; __half2 h[4]; };

static __device__ __forceinline__ void atomAddF(float* p, float v) {
    unsafeAtomicAdd(p, v);   // global_atomic_add_f32 on gfx950
}

// ---- pass A: per-chunk histogram (+ fp16 conversions piggy-backed) --------
__global__ __launch_bounds__(256) void bin_count_kernel(
        const int* __restrict__ dst, int E, int CH,
        int* __restrict__ hist, int K,
        const float2* __restrict__ table2, __half2* __restrict__ th2, int n2,
        const float* __restrict__ W1, const float* __restrict__ W2,
        __half* __restrict__ w1t, __half* __restrict__ w2t) {
    __shared__ int lh[MAXK];
    int tid = threadIdx.x;
    for (int i = tid; i < K; i += 256) lh[i] = 0;
    __syncthreads();
    int stride = gridDim.x * 256;
    for (int i = blockIdx.x * 256 + tid; i < n2; i += stride)
        th2[i] = __float22half2_rn(table2[i]);
    for (int i = blockIdx.x * 256 + tid; i < DD * DD; i += stride) {
        int n = i >> 6, k = i & 63;
        w1t[i] = __float2half(W1[k * DD + n]);   // WT[n][k]
        w2t[i] = __float2half(W2[k * DD + n]);
    }
    int e0 = blockIdx.x * CH;
    int e1 = min(E, e0 + CH);
    for (int e = e0 + tid; e < e1; e += 256)
        atomicAdd(&lh[((unsigned)dst[e]) >> 8], 1);
    __syncthreads();
    for (int b = tid; b < K; b += 256)
        hist[blockIdx.x * MAXK + b] = lh[b];     // coalesced private row
}

// ---- pass B0: bucket totals (parallel, coalesced) + zero outacc -----------
__global__ __launch_bounds__(256) void totals_kernel(
        const int* __restrict__ hist, int* __restrict__ bts,
        float* __restrict__ outacc, int K, int G2) {
    int g0 = blockIdx.x * 256 + threadIdx.x;
    int stride = gridDim.x * 256;
    for (int i = g0; i < G2; i += stride) outacc[i] = 0.f;
    for (int b = g0; b < K; b += stride) {
        int s = 0;
        for (int blk = 0; blk < NBLK; ++blk) s += hist[blk * MAXK + b];
        bts[b] = s;
    }
}

// ---- pass B1: exclusive scan of bts[K] -> bb; bb[K] = E -------------------
__global__ __launch_bounds__(256) void scan_bb_kernel(
        const int* __restrict__ bts, int* __restrict__ bb, int K, int E) {
    __shared__ int part[256];
    int tid = threadIdx.x;
    int CH2 = (K + 255) / 256;
    int base = tid * CH2;
    int s = 0;
    for (int i = 0; i < CH2; ++i) {
        int idx = base + i;
        if (idx < K) s += bts[idx];
    }
    part[tid] = s;
    __syncthreads();
    if (tid < 64) {
        int carry = 0;
        for (int c = 0; c < 4; ++c) {
            int orig = part[c * 64 + tid];
            int v = orig;
            #pragma unroll
            for (int off = 1; off < 64; off <<= 1) {
                int t = __shfl_up(v, off);
                if (tid >= off) v += t;
            }
            int tot = __shfl(v, 63);
            part[c * 64 + tid] = v - orig + carry;   // exclusive
            carry += tot;
        }
    }
    __syncthreads();
    int run = part[tid];
    for (int i = 0; i < CH2; ++i) {
        int idx = base + i;
        if (idx < K) {
            bb[idx] = run;
            run += bts[idx];
        }
    }
    if (tid == 0) bb[K] = E;
}

// ---- pass B2: one WAVE per bucket scans across blocks -> cur[blk][bucket] -
__global__ __launch_bounds__(256) void scanB_kernel(
        const int* __restrict__ hist, const int* __restrict__ bb,
        int* __restrict__ cur, int K) {
    int wid = (blockIdx.x * 256 + threadIdx.x) >> 6;   // global wave id = bucket
    int lane = threadIdx.x & 63;
    if (wid >= K) return;
    int b = wid;
    const int PER = NBLK / 64;    // 16 blocks per lane
    int v[PER];
    int sum = 0;
    #pragma unroll
    for (int i = 0; i < PER; ++i) {
        v[i] = hist[(lane * PER + i) * MAXK + b];
        sum += v[i];
    }
    int pref = sum;
    #pragma unroll
    for (int off = 1; off < 64; off <<= 1) {
        int t = __shfl_up(pref, off);
        if (lane >= off) pref += t;
    }
    int run = bb[b] + pref - sum;   // exclusive
    #pragma unroll
    for (int i = 0; i < PER; ++i) {
        cur[(lane * PER + i) * MAXK + b] = run;
        run += v[i];
    }
}

// ---- pass C: append packed pairs; cursors in LDS (block-private cells) ----
__global__ __launch_bounds__(256) void fill_kernel(
        const int* __restrict__ src, const int* __restrict__ dst, int E, int CH,
        const int* __restrict__ cur, int* __restrict__ pairbuf, int K) {
    __shared__ int lcur[MAXK];
    int tid = threadIdx.x;
    for (int b = tid; b < K; b += 256)
        lcur[b] = cur[blockIdx.x * MAXK + b];
    __syncthreads();
    int e0 = blockIdx.x * CH;
    int e1 = min(E, e0 + CH);
    for (int e = e0 + tid; e < e1; e += 256) {
        int s = src[e], d = dst[e];
        int pos = atomicAdd(&lcur[((unsigned)d) >> 8], 1);
        pairbuf[pos] = s | ((d & 255) << 24);
    }
}

// ---- pass D: per-bucket padded CSR build + rowinfo/xd/g0h (coalesced) -----
__global__ __launch_bounds__(256) void build_csr_kernel(
        const int* __restrict__ pairbuf, const int* __restrict__ bnd,
        const int* __restrict__ x, int2* __restrict__ rowinfo,
        float2* __restrict__ xd, const float4* __restrict__ th4,
        int* __restrict__ csr_src, __half* __restrict__ g0h,
        __half* __restrict__ g1h, int N) {
    __shared__ int cnt[256], basel[256], curl[256];
    __shared__ float ldinv[256];
    __shared__ int   lxi[256];
    int tid = threadIdx.x;
    int b = blockIdx.x;
    int node0 = b << 8;
    cnt[tid] = 0;
    __syncthreads();
    int bb0 = bnd[b], bb1 = bnd[b + 1];
    for (int i = bb0 + tid; i < bb1; i += 256)
        atomicAdd(&cnt[((unsigned)pairbuf[i]) >> 24], 1);
    __syncthreads();
    int c  = cnt[tid];
    int pc = (c + 3) & ~3;              // padded count
    {
        __syncthreads();
        basel[tid] = pc;
        __syncthreads();
        if (tid < 64) {
            int carry = 0;
            for (int cc = 0; cc < 4; ++cc) {
                int orig = basel[cc * 64 + tid];
                int v = orig;
                #pragma unroll
                for (int off = 1; off < 64; off <<= 1) {
                    int t = __shfl_up(v, off);
                    if (tid >= off) v += t;
                }
                int tot = __shfl(v, 63);
                cnt[cc * 64 + tid] = v - orig + carry;   // exclusive
                carry += tot;
            }
        }
        __syncthreads();
    }
    int cb0 = ((bb0 + 3) & ~3) + SLACK * b;   // aligned csr base for bucket
    int node = node0 + tid;
    int myBase = cb0 + cnt[tid];
    curl[tid] = myBase;
    ldinv[tid] = 0.f;
    lxi[tid] = 0;
    if (node < N) {
        float di = rsqrtf((float)c + 1.0f);
        int xi = x[node];
        rowinfo[node] = make_int2(myBase, pc);
        xd[node] = make_float2(di, __int_as_float(xi));
        ldinv[tid] = di;
        lxi[tid] = xi;
        for (int t = c; t < pc; ++t) csr_src[myBase + t] = N;   // sentinel pad
    } else if (node == N) {
        xd[N] = make_float2(0.0f, __int_as_float(0));           // zero weight
        float2* z1 = (float2*)(g1h + (size_t)N * DD);           // zero row N
        float2* z0 = (float2*)(g0h + (size_t)N * DD);
        for (int t = 0; t < DD / 4; ++t) {
            z1[t] = make_float2(0.f, 0.f);
            z0[t] = make_float2(0.f, 0.f);
        }
    }
    __syncthreads();
    for (int i = bb0 + tid; i < bb1; i += 256) {
        int pk = pairbuf[i];
        int pos = atomicAdd(&curl[((unsigned)pk) >> 24], 1);
        csr_src[pos] = pk & 0x00FFFFFF;
    }
    // g0h[node] = dinv * fp16(table[x]) — coalesced 16B-chunk writes
    float4* g0h4 = (float4*)g0h;
    for (int idx = tid; idx < 256 * 8; idx += 256) {
        int n = idx >> 3, ch = idx & 7;
        int gn = node0 + n;
        if (gn < N) {
            H8 tv; tv.f = th4[(size_t)lxi[n] * 8 + ch];
            __half2 dh = __float2half2_rn(ldinv[n]);
            #pragma unroll
            for (int t = 0; t < 4; ++t) tv.h[t] = __hmul2(dh, tv.h[t]);
            g0h4[(size_t)gn * 8 + ch] = tv.f;
        }
    }
}

// ---------------- layer 1: gather g0h, MFMA MLP, g1h = f16(dv*h1) ----------
// identical gather structure to layer2 (single-load per edge)
__global__ __launch_bounds__(256, 8) void layer1_kernel(
        const int2* __restrict__ rowinfo,
        const int* __restrict__ csr_src, const float2* __restrict__ xd,
        const float4* __restrict__ g0h4, const __half* __restrict__ wt,
        const float* __restrict__ bias, __half* __restrict__ g1h, int N) {
    __shared__ float4 Hs4[32 * 9];   // padded stride 9
    __shared__ float dvs[32];
    int row0 = blockIdx.x * 32;
    int tid = threadIdx.x;
    int node_l = tid >> 3, j3 = tid & 7;
    int node = row0 + node_l;
    H8 acc0, acc1, acc2, acc3;
    acc0.f = make_float4(0.f, 0.f, 0.f, 0.f);
    acc1.f = acc0.f; acc2.f = acc0.f; acc3.f = acc0.f;
    if (node < N) {
        float di = xd[node].x;
        if (j3 == 0) dvs[node_l] = di;
        acc0.f = g0h4[(size_t)node * 8 + j3];   // self term (= dinv*t[x])
        int2 ri = rowinfo[node];
        const int4* cs = (const int4*)(csr_src + ri.x);
        int nq = ri.y >> 2;
        int q = 0;
        for (; q + 1 < nq; q += 2) {
            int4 sA = cs[q], sB = cs[q + 1];
            H8 u0, u1, u2, u3, u4, u5, u6, u7;
            u0.f = g0h4[(size_t)sA.x * 8 + j3];
            u1.f = g0h4[(size_t)sA.y * 8 + j3];
            u2.f = g0h4[(size_t)sA.z * 8 + j3];
            u3.f = g0h4[(size_t)sA.w * 8 + j3];
            u4.f = g0h4[(size_t)sB.x * 8 + j3];
            u5.f = g0h4[(size_t)sB.y * 8 + j3];
            u6.f = g0h4[(size_t)sB.z * 8 + j3];
            u7.f = g0h4[(size_t)sB.w * 8 + j3];
            #pragma unroll
            for (int t = 0; t < 4; ++t) {
                acc0.h[t] = __hadd2(acc0.h[t], u0.h[t]);
                acc1.h[t] = __hadd2(acc1.h[t], u1.h[t]);
                acc2.h[t] = __hadd2(acc2.h[t], u2.h[t]);
                acc3.h[t] = __hadd2(acc3.h[t], u3.h[t]);
                acc0.h[t] = __hadd2(acc0.h[t], u4.h[t]);
                acc1.h[t] = __hadd2(acc1.h[t], u5.h[t]);
                acc2.h[t] = __hadd2(acc2.h[t], u6.h[t]);
                acc3.h[t] = __hadd2(acc3.h[t], u7.h[t]);
            }
        }
        if (q < nq) {
            int4 sA = cs[q];
            H8 u0, u1, u2, u3;
            u0.f = g0h4[(size_t)sA.x * 8 + j3];
            u1.f = g0h4[(size_t)sA.y * 8 + j3];
            u2.f = g0h4[(size_t)sA.z * 8 + j3];
            u3.f = g0h4[(size_t)sA.w * 8 + j3];
            #pragma unroll
            for (int t = 0; t < 4; ++t) {
                acc0.h[t] = __hadd2(acc0.h[t], u0.h[t]);
                acc1.h[t] = __hadd2(acc1.h[t], u1.h[t]);
                acc2.h[t] = __hadd2(acc2.h[t], u2.h[t]);
                acc3.h[t] = __hadd2(acc3.h[t], u3.h[t]);
            }
        }
        __half2 dih = __float2half2_rn(di);
        #pragma unroll
        for (int t = 0; t < 4; ++t)
            acc0.h[t] = __hmul2(dih, __hadd2(__hadd2(acc0.h[t], acc1.h[t]),
                                             __hadd2(acc2.h[t], acc3.h[t])));
    }
    Hs4[node_l * 9 + j3] = acc0.f;
    __syncthreads();

    // MFMA MLP: 2 tiles of 16 rows; each wave does cols wave*16..+15, K=64.
    int wave = tid >> 6, lane = tid & 63;
    int m = lane & 15, quad = lane >> 4;
    int ncol = wave * 16 + m;
    F4H8 b0, b1;
    const float4* WT4 = (const float4*)wt;
    b0.f = WT4[ncol * 8 + quad];
    b1.f = WT4[ncol * 8 + 4 + quad];
    float bb_ = bias[ncol];
    #pragma unroll
    for (int t = 0; t < 2; ++t) {
        F4H8 a0, a1;
        a0.f = Hs4[(t * 16 + m) * 9 + quad];
        a1.f = Hs4[(t * 16 + m) * 9 + 4 + quad];
        float4_t acc = {0.f, 0.f, 0.f, 0.f};
        acc = __builtin_amdgcn_mfma_f32_16x16x32_f16(a0.h, b0.h, acc, 0, 0, 0);
        acc = __builtin_amdgcn_mfma_f32_16x16x32_f16(a1.h, b1.h, acc, 0, 0, 0);
        #pragma unroll
        for (int reg = 0; reg < 4; ++reg) {
            int row = t * 16 + quad * 4 + reg;
            int grow = row0 + row;
            if (grow < N) {
                float h = fmaxf(acc[reg] + bb_, 0.0f);
                g1h[(size_t)grow * DD + ncol] = __float2half(dvs[row] * h);
            }
        }
    }
}

// -------- layer 2 + pool: gather g1h, MFMA MLP, Wlin dot + segmented pool ---
__global__ __launch_bounds__(256, 8) void layer2_pool_kernel(
        const int2* __restrict__ rowinfo,
        const int* __restrict__ csr_src, const float2* __restrict__ xd,
        const float4* __restrict__ g1h4, const __half* __restrict__ wt,
        const float* __restrict__ bias, const int* __restrict__ batch,
        const float* __restrict__ Wlin, float* __restrict__ outacc, int N) {
    __shared__ float4 Hs4[32 * 9];       // padded stride 9
    __shared__ float lp0[128], lp1[128]; // [wave][row]
    __shared__ float p0s[32], p1s[32];
    __shared__ int   bat[32];
    int row0 = blockIdx.x * 32;
    int tid = threadIdx.x;
    int node_l = tid >> 3, j3 = tid & 7;
    int node = row0 + node_l;
    H8 acc0, acc1, acc2, acc3;
    acc0.f = make_float4(0.f, 0.f, 0.f, 0.f);
    acc1.f = acc0.f; acc2.f = acc0.f; acc3.f = acc0.f;
    if (node < N) {
        float di = xd[node].x;
        acc0.f = g1h4[(size_t)node * 8 + j3];   // self term, weight 1
        int2 ri = rowinfo[node];
        const int4* cs = (const int4*)(csr_src + ri.x);
        int nq = ri.y >> 2;
        int q = 0;
        for (; q + 1 < nq; q += 2) {
            int4 sA = cs[q], sB = cs[q + 1];
            H8 u0, u1, u2, u3, u4, u5, u6, u7;
            u0.f = g1h4[(size_t)sA.x * 8 + j3];
            u1.f = g1h4[(size_t)sA.y * 8 + j3];
            u2.f = g1h4[(size_t)sA.z * 8 + j3];
            u3.f = g1h4[(size_t)sA.w * 8 + j3];
            u4.f = g1h4[(size_t)sB.x * 8 + j3];
            u5.f = g1h4[(size_t)sB.y * 8 + j3];
            u6.f = g1h4[(size_t)sB.z * 8 + j3];
            u7.f = g1h4[(size_t)sB.w * 8 + j3];
            #pragma unroll
            for (int t = 0; t < 4; ++t) {
                acc0.h[t] = __hadd2(acc0.h[t], u0.h[t]);
                acc1.h[t] = __hadd2(acc1.h[t], u1.h[t]);
                acc2.h[t] = __hadd2(acc2.h[t], u2.h[t]);
                acc3.h[t] = __hadd2(acc3.h[t], u3.h[t]);
                acc0.h[t] = __hadd2(acc0.h[t], u4.h[t]);
                acc1.h[t] = __hadd2(acc1.h[t], u5.h[t]);
                acc2.h[t] = __hadd2(acc2.h[t], u6.h[t]);
                acc3.h[t] = __hadd2(acc3.h[t], u7.h[t]);
            }
        }
        if (q < nq) {
            int4 sA = cs[q];
            H8 u0, u1, u2, u3;
            u0.f = g1h4[(size_t)sA.x * 8 + j3];
            u1.f = g1h4[(size_t)sA.y * 8 + j3];
            u2.f = g1h4[(size_t)sA.z * 8 + j3];
            u3.f = g1h4[(size_t)sA.w * 8 + j3];
            #pragma unroll
            for (int t = 0; t < 4; ++t) {
                acc0.h[t] = __hadd2(acc0.h[t], u0.h[t]);
                acc1.h[t] = __hadd2(acc1.h[t], u1.h[t]);
                acc2.h[t] = __hadd2(acc2.h[t], u2.h[t]);
                acc3.h[t] = __hadd2(acc3.h[t], u3.h[t]);
            }
        }
        __half2 dih = __float2half2_rn(di);
        #pragma unroll
        for (int t = 0; t < 4; ++t)
            acc0.h[t] = __hmul2(dih, __hadd2(__hadd2(acc0.h[t], acc1.h[t]),
                                             __hadd2(acc2.h[t], acc3.h[t])));
    }
    Hs4[node_l * 9 + j3] = acc0.f;
    __syncthreads();

    int wave = tid >> 6, lane = tid & 63;
    int m = lane & 15, quad = lane >> 4;
    int ncol = wave * 16 + m;
    F4H8 b0, b1;
    const float4* WT4 = (const float4*)wt;
    b0.f = WT4[ncol * 8 + quad];
    b1.f = WT4[ncol * 8 + 4 + quad];
    float bb_  = bias[ncol];
    float wl0 = Wlin[ncol * 2 + 0];
    float wl1 = Wlin[ncol * 2 + 1];
    #pragma unroll
    for (int t = 0; t < 2; ++t) {
        F4H8 a0, a1;
        a0.f = Hs4[(t * 16 + m) * 9 + quad];
        a1.f = Hs4[(t * 16 + m) * 9 + 4 + quad];
        float4_t acc = {0.f, 0.f, 0.f, 0.f};
        acc = __builtin_amdgcn_mfma_f32_16x16x32_f16(a0.h, b0.h, acc, 0, 0, 0);
        acc = __builtin_amdgcn_mfma_f32_16x16x32_f16(a1.h, b1.h, acc, 0, 0, 0);
        #pragma unroll
        for (int reg = 0; reg < 4; ++reg) {
            int row = t * 16 + quad * 4 + reg;
            int grow = row0 + row;
            float h = (grow < N) ? fmaxf(acc[reg] + bb_, 0.0f) : 0.0f;
            float p0 = h * wl0;
            float p1 = h * wl1;
            #pragma unroll
            for (int off = 8; off >= 1; off >>= 1) {   // sum over 16 cols (m)
                p0 += __shfl_xor(p0, off);
                p1 += __shfl_xor(p1, off);
            }
            if (m == 0) {
                lp0[wave * 32 + row] = p0;
                lp1[wave * 32 + row] = p1;
            }
        }
    }
    __syncthreads();
    if (tid < 32) {
        int grow = row0 + tid;
        p0s[tid] = lp0[tid] + lp0[32 + tid] + lp0[64 + tid] + lp0[96 + tid];
        p1s[tid] = lp1[tid] + lp1[32 + tid] + lp1[64 + tid] + lp1[96 + tid];
        bat[tid] = (grow < N) ? batch[grow] : -1;
    }
    __syncthreads();
    if (tid < 32) {
        int bg = bat[tid];
        bool head = (bg >= 0) && (tid == 0 || bat[tid - 1] != bg);
        if (head) {
            float s0 = 0.f, s1 = 0.f;
            for (int k = tid; k < 32 && bat[k] == bg; ++k) {
                s0 += p0s[k];
                s1 += p1s[k];
            }
            atomAddF(&outacc[bg * 2 + 0], s0);
            atomAddF(&outacc[bg * 2 + 1], s1);
        }
    }
}

// counts via binary search on sorted batch; then divide + blin
__global__ void final_kernel(const float* __restrict__ outacc,
                             const int* __restrict__ batch,
                             const float* __restrict__ blin,
                             float* __restrict__ out, int G, int N) {
    int t = blockIdx.x * blockDim.x + threadIdx.x;
    if (t >= G * 2) return;
    int g = t >> 1, c = t & 1;
    int lo = 0, hi = N;
    while (lo < hi) { int m = (lo + hi) >> 1; if (batch[m] < g) lo = m + 1; else hi = m; }
    int lo2 = lo, hi2 = N;
    while (lo2 < hi2) { int m = (lo2 + hi2) >> 1; if (batch[m] < g + 1) lo2 = m + 1; else hi2 = m; }
    float cnt = (float)(lo2 - lo);
    out[t] = outacc[t] / fmaxf(cnt, 1.0f) + blin[c];
}

extern "C" void kernel_launch(void* const* d_in, const int* in_sizes, int n_in,
                              void* d_out, int out_size, void* d_ws, size_t ws_size,
                              hipStream_t stream) {
    const int*   x      = (const int*)d_in[0];
    const int*   ei     = (const int*)d_in[1];   // [2,E] row-major
    const int*   batch  = (const int*)d_in[3];
    const float* table  = (const float*)d_in[4];
    const float* W1     = (const float*)d_in[5];
    const float* b1     = (const float*)d_in[6];
    const float* W2     = (const float*)d_in[7];
    const float* b2     = (const float*)d_in[8];
    const float* Wlin   = (const float*)d_in[9];
    const float* blin   = (const float*)d_in[10];
    float* out = (float*)d_out;

    const int N = in_sizes[0];
    const int E = in_sizes[2];          // edge_type count == E
    const int G = out_size / 2;
    const int TBL = in_sizes[4];        // VOCAB*DD floats

    const int* src = ei;
    const int* dst = ei + E;

    const int K = (N + BKT - 1) / BKT;  // buckets
    const int M = NBLK * MAXK;          // (block, bucket) cells
    const int CH = (E + NBLK - 1) / NBLK;
    const int CSRSZ = E + SLACK * K + 64;

    // workspace layout (keep 16-B alignment for b128 reads)
    __half* g0h     = (__half*)d_ws;                      // (N+1)*64 halves
    __half* g1h     = g0h + (size_t)(N + 1) * DD;         // (N+1)*64 halves
    __half* th      = g1h + (size_t)(N + 1) * DD;         // TBL halves
    __half* w1t     = th + TBL;                           // 4096 halves
    __half* w2t     = w1t + DD * DD;                      // 4096 halves
    int*    pairbuf = (int*)(w2t + DD * DD);              // E ints
    int*    csr_src = pairbuf + E;                        // CSRSZ ints
    int2*   rowinfo = (int2*)(csr_src + CSRSZ);           // N int2
    float2* xd      = (float2*)(rowinfo + N);             // N+1 float2
    float*  outacc  = (float*)(xd + N + 1);               // 2G (zeroed in totals)
    int*    bb      = (int*)(outacc + 2 * G);             // K+1
    int*    bts     = bb + K + 1;                         // K
    int*    hist    = bts + K;                            // M
    int*    cur     = hist + M;                           // M

    const int BT = 256;

    // partition: per-chunk histogram -> totals(+outacc zero) -> bucket scan
    //            -> per-bucket block scan (wave-parallel) -> append -> sort
    bin_count_kernel<<<NBLK, BT, 0, stream>>>(dst, E, CH, hist, K,
                                              (const float2*)table,
                                              (__half2*)th, TBL / 2,
                                              W1, W2, w1t, w2t);
    totals_kernel<<<16, BT, 0, stream>>>(hist, bts, outacc, K, 2 * G);
    scan_bb_kernel<<<1, BT, 0, stream>>>(bts, bb, K, E);
    scanB_kernel<<<(K * 64 + BT - 1) / BT, BT, 0, stream>>>(hist, bb, cur, K);
    fill_kernel<<<NBLK, BT, 0, stream>>>(src, dst, E, CH, cur, pairbuf, K);
    build_csr_kernel<<<K, BT, 0, stream>>>(pairbuf, bb, x, rowinfo, xd,
                                           (const float4*)th, csr_src,
                                           g0h, g1h, N);

    // layer 1 (gather g0h + MFMA-MLP + relu; writes g1h = fp16(dinv*h1))
    int gRow = (N + 31) / 32;
    layer1_kernel<<<gRow, BT, 0, stream>>>(rowinfo, csr_src, xd,
                                           (const float4*)g0h, w1t, b1, g1h, N);
    // layer 2 (agg+MFMA-MLP+relu+pool fused)
    layer2_pool_kernel<<<gRow, BT, 0, stream>>>(rowinfo, csr_src, xd,
                                                (const float4*)g1h, w2t, b2,
                                                batch, Wlin, outacc, N);
    // final
    final_kernel<<<(G * 2 + BT - 1) / BT, BT, 0, stream>>>(outacc, batch, blin,
                                                           out, G, N);
}

// Round 16
// 248.405 us; speedup vs baseline: 1.1196x; 1.1196x over previous
//
#include <hip/hip_runtime.h>
#include <hip/hip_fp16.h>

// ---------------------------------------------------------------------------
// GCN forward on MI355X — round 16.
//  * totals_kernel -> wave-per-bucket (r15's version looped 1024 strided loads
//    on 782 threads over 16 blocks: ~+25us serial hotspot that masked the
//    NBLK=1024 bin_count/fill gains).  Butterfly-reduce per wave.
//  * Everything else as round 15 (NBLK=1024, g0h materialization, 8-lane b128
//    fp16 gather, MFMA MLP, fused pool).
//  * Note: the ~44us fillBufferAligned dispatches are the harness's 256MiB
//    d_ws poison — fixed floor, not ours.
// ---------------------------------------------------------------------------

#define DD 64          // feature dim
#define BKT 256        // nodes per bucket (CSR build)
#define MAXK 1024      // max buckets; hist/cur row stride
#define NBLK 1024      // partition blocks (chunks)
#define SLACK 772      // per-bucket csr slack: 3*256 pad + 4 alignment

typedef _Float16 half8_t __attribute__((ext_vector_type(8)));
typedef float float4_t __attribute__((ext_vector_type(4)));
union F4H8 { float4 f; half8_t h; };
union H8   { float4 f; __half2 h[4]; };

static __device__ __forceinline__ void atomAddF(float* p, float v) {
    unsafeAtomicAdd(p, v);   // global_atomic_add_f32 on gfx950
}

// ---- pass A: per-chunk histogram (+ fp16 conversions piggy-backed) --------
__global__ __launch_bounds__(256) void bin_count_kernel(
        const int* __restrict__ dst, int E, int CH,
        int* __restrict__ hist, int K,
        const float2* __restrict__ table2, __half2* __restrict__ th2, int n2,
        const float* __restrict__ W1, const float* __restrict__ W2,
        __half* __restrict__ w1t, __half* __restrict__ w2t) {
    __shared__ int lh[MAXK];
    int tid = threadIdx.x;
    for (int i = tid; i < K; i += 256) lh[i] = 0;
    __syncthreads();
    int stride = gridDim.x * 256;
    for (int i = blockIdx.x * 256 + tid; i < n2; i += stride)
        th2[i] = __float22half2_rn(table2[i]);
    for (int i = blockIdx.x * 256 + tid; i < DD * DD; i += stride) {
        int n = i >> 6, k = i & 63;
        w1t[i] = __float2half(W1[k * DD + n]);   // WT[n][k]
        w2t[i] = __float2half(W2[k * DD + n]);
    }
    int e0 = blockIdx.x * CH;
    int e1 = min(E, e0 + CH);
    for (int e = e0 + tid; e < e1; e += 256)
        atomicAdd(&lh[((unsigned)dst[e]) >> 8], 1);
    __syncthreads();
    for (int b = tid; b < K; b += 256)
        hist[blockIdx.x * MAXK + b] = lh[b];     // coalesced private row
}

// ---- pass B0: bucket totals, one WAVE per bucket; zero outacc -------------
__global__ __launch_bounds__(256) void totals_kernel(
        const int* __restrict__ hist, int* __restrict__ bts,
        float* __restrict__ outacc, int K, int G2) {
    int gt = blockIdx.x * 256 + threadIdx.x;
    if (gt < G2) outacc[gt] = 0.f;
    int wid = gt >> 6;            // wave id = bucket
    int lane = threadIdx.x & 63;
    if (wid >= K) return;
    const int PER = NBLK / 64;    // 16 cells per lane
    int s = 0;
    #pragma unroll
    for (int i = 0; i < PER; ++i)
        s += hist[(lane * PER + i) * MAXK + wid];
    #pragma unroll
    for (int off = 32; off >= 1; off >>= 1)
        s += __shfl_xor(s, off);
    if (lane == 0) bts[wid] = s;
}

// ---- pass B1: exclusive scan of bts[K] -> bb; bb[K] = E -------------------
__global__ __launch_bounds__(256) void scan_bb_kernel(
        const int* __restrict__ bts, int* __restrict__ bb, int K, int E) {
    __shared__ int part[256];
    int tid = threadIdx.x;
    int CH2 = (K + 255) / 256;
    int base = tid * CH2;
    int s = 0;
    for (int i = 0; i < CH2; ++i) {
        int idx = base + i;
        if (idx < K) s += bts[idx];
    }
    part[tid] = s;
    __syncthreads();
    if (tid < 64) {
        int carry = 0;
        for (int c = 0; c < 4; ++c) {
            int orig = part[c * 64 + tid];
            int v = orig;
            #pragma unroll
            for (int off = 1; off < 64; off <<= 1) {
                int t = __shfl_up(v, off);
                if (tid >= off) v += t;
            }
            int tot = __shfl(v, 63);
            part[c * 64 + tid] = v - orig + carry;   // exclusive
            carry += tot;
        }
    }
    __syncthreads();
    int run = part[tid];
    for (int i = 0; i < CH2; ++i) {
        int idx = base + i;
        if (idx < K) {
            bb[idx] = run;
            run += bts[idx];
        }
    }
    if (tid == 0) bb[K] = E;
}

// ---- pass B2: one WAVE per bucket scans across blocks -> cur[blk][bucket] -
__global__ __launch_bounds__(256) void scanB_kernel(
        const int* __restrict__ hist, const int* __restrict__ bb,
        int* __restrict__ cur, int K) {
    int wid = (blockIdx.x * 256 + threadIdx.x) >> 6;   // global wave id = bucket
    int lane = threadIdx.x & 63;
    if (wid >= K) return;
    int b = wid;
    const int PER = NBLK / 64;    // 16 blocks per lane
    int v[PER];
    int sum = 0;
    #pragma unroll
    for (int i = 0; i < PER; ++i) {
        v[i] = hist[(lane * PER + i) * MAXK + b];
        sum += v[i];
    }
    int pref = sum;
    #pragma unroll
    for (int off = 1; off < 64; off <<= 1) {
        int t = __shfl_up(pref, off);
        if (lane >= off) pref += t;
    }
    int run = bb[b] + pref - sum;   // exclusive
    #pragma unroll
    for (int i = 0; i < PER; ++i) {
        cur[(lane * PER + i) * MAXK + b] = run;
        run += v[i];
    }
}

// ---- pass C: append packed pairs; cursors in LDS (block-private cells) ----
__global__ __launch_bounds__(256) void fill_kernel(
        const int* __restrict__ src, const int* __restrict__ dst, int E, int CH,
        const int* __restrict__ cur, int* __restrict__ pairbuf, int K) {
    __shared__ int lcur[MAXK];
    int tid = threadIdx.x;
    for (int b = tid; b < K; b += 256)
        lcur[b] = cur[blockIdx.x * MAXK + b];
    __syncthreads();
    int e0 = blockIdx.x * CH;
    int e1 = min(E, e0 + CH);
    for (int e = e0 + tid; e < e1; e += 256) {
        int s = src[e], d = dst[e];
        int pos = atomicAdd(&lcur[((unsigned)d) >> 8], 1);
        pairbuf[pos] = s | ((d & 255) << 24);
    }
}

// ---- pass D: per-bucket padded CSR build + rowinfo/xd/g0h (coalesced) -----
__global__ __launch_bounds__(256) void build_csr_kernel(
        const int* __restrict__ pairbuf, const int* __restrict__ bnd,
        const int* __restrict__ x, int2* __restrict__ rowinfo,
        float2* __restrict__ xd, const float4* __restrict__ th4,
        int* __restrict__ csr_src, __half* __restrict__ g0h,
        __half* __restrict__ g1h, int N) {
    __shared__ int cnt[256], basel[256], curl[256];
    __shared__ float ldinv[256];
    __shared__ int   lxi[256];
    int tid = threadIdx.x;
    int b = blockIdx.x;
    int node0 = b << 8;
    cnt[tid] = 0;
    __syncthreads();
    int bb0 = bnd[b], bb1 = bnd[b + 1];
    for (int i = bb0 + tid; i < bb1; i += 256)
        atomicAdd(&cnt[((unsigned)pairbuf[i]) >> 24], 1);
    __syncthreads();
    int c  = cnt[tid];
    int pc = (c + 3) & ~3;              // padded count
    {
        __syncthreads();
        basel[tid] = pc;
        __syncthreads();
        if (tid < 64) {
            int carry = 0;
            for (int cc = 0; cc < 4; ++cc) {
                int orig = basel[cc * 64 + tid];
                int v = orig;
                #pragma unroll
                for (int off = 1; off < 64; off <<= 1) {
                    int t = __shfl_up(v, off);
                    if (tid >= off) v += t;
                }
                int tot = __shfl(v, 63);
                cnt[cc * 64 + tid] = v - orig + carry;   // exclusive
                carry += tot;
            }
        }
        __syncthreads();
    }
    int cb0 = ((bb0 + 3) & ~3) + SLACK * b;   // aligned csr base for bucket
    int node = node0 + tid;
    int myBase = cb0 + cnt[tid];
    curl[tid] = myBase;
    ldinv[tid] = 0.f;
    lxi[tid] = 0;
    if (node < N) {
        float di = rsqrtf((float)c + 1.0f);
        int xi = x[node];
        rowinfo[node] = make_int2(myBase, pc);
        xd[node] = make_float2(di, __int_as_float(xi));
        ldinv[tid] = di;
        lxi[tid] = xi;
        for (int t = c; t < pc; ++t) csr_src[myBase + t] = N;   // sentinel pad
    } else if (node == N) {
        xd[N] = make_float2(0.0f, __int_as_float(0));           // zero weight
        float2* z1 = (float2*)(g1h + (size_t)N * DD);           // zero row N
        float2* z0 = (float2*)(g0h + (size_t)N * DD);
        for (int t = 0; t < DD / 4; ++t) {
            z1[t] = make_float2(0.f, 0.f);
            z0[t] = make_float2(0.f, 0.f);
        }
    }
    __syncthreads();
    for (int i = bb0 + tid; i < bb1; i += 256) {
        int pk = pairbuf[i];
        int pos = atomicAdd(&curl[((unsigned)pk) >> 24], 1);
        csr_src[pos] = pk & 0x00FFFFFF;
    }
    // g0h[node] = dinv * fp16(table[x]) — coalesced 16B-chunk writes
    float4* g0h4 = (float4*)g0h;
    for (int idx = tid; idx < 256 * 8; idx += 256) {
        int n = idx >> 3, ch = idx & 7;
        int gn = node0 + n;
        if (gn < N) {
            H8 tv; tv.f = th4[(size_t)lxi[n] * 8 + ch];
            __half2 dh = __float2half2_rn(ldinv[n]);
            #pragma unroll
            for (int t = 0; t < 4; ++t) tv.h[t] = __hmul2(dh, tv.h[t]);
            g0h4[(size_t)gn * 8 + ch] = tv.f;
        }
    }
}

// ---------------- layer 1: gather g0h, MFMA MLP, g1h = f16(dv*h1) ----------
__global__ __launch_bounds__(256, 8) void layer1_kernel(
        const int2* __restrict__ rowinfo,
        const int* __restrict__ csr_src, const float2* __restrict__ xd,
        const float4* __restrict__ g0h4, const __half* __restrict__ wt,
        const float* __restrict__ bias, __half* __restrict__ g1h, int N) {
    __shared__ float4 Hs4[32 * 9];   // padded stride 9
    __shared__ float dvs[32];
    int row0 = blockIdx.x * 32;
    int tid = threadIdx.x;
    int node_l = tid >> 3, j3 = tid & 7;
    int node = row0 + node_l;
    H8 acc0, acc1, acc2, acc3;
    acc0.f = make_float4(0.f, 0.f, 0.f, 0.f);
    acc1.f = acc0.f; acc2.f = acc0.f; acc3.f = acc0.f;
    if (node < N) {
        float di = xd[node].x;
        if (j3 == 0) dvs[node_l] = di;
        acc0.f = g0h4[(size_t)node * 8 + j3];   // self term (= dinv*t[x])
        int2 ri = rowinfo[node];
        const int4* cs = (const int4*)(csr_src + ri.x);
        int nq = ri.y >> 2;
        int q = 0;
        for (; q + 1 < nq; q += 2) {
            int4 sA = cs[q], sB = cs[q + 1];
            H8 u0, u1, u2, u3, u4, u5, u6, u7;
            u0.f = g0h4[(size_t)sA.x * 8 + j3];
            u1.f = g0h4[(size_t)sA.y * 8 + j3];
            u2.f = g0h4[(size_t)sA.z * 8 + j3];
            u3.f = g0h4[(size_t)sA.w * 8 + j3];
            u4.f = g0h4[(size_t)sB.x * 8 + j3];
            u5.f = g0h4[(size_t)sB.y * 8 + j3];
            u6.f = g0h4[(size_t)sB.z * 8 + j3];
            u7.f = g0h4[(size_t)sB.w * 8 + j3];
            #pragma unroll
            for (int t = 0; t < 4; ++t) {
                acc0.h[t] = __hadd2(acc0.h[t], u0.h[t]);
                acc1.h[t] = __hadd2(acc1.h[t], u1.h[t]);
                acc2.h[t] = __hadd2(acc2.h[t], u2.h[t]);
                acc3.h[t] = __hadd2(acc3.h[t], u3.h[t]);
                acc0.h[t] = __hadd2(acc0.h[t], u4.h[t]);
                acc1.h[t] = __hadd2(acc1.h[t], u5.h[t]);
                acc2.h[t] = __hadd2(acc2.h[t], u6.h[t]);
                acc3.h[t] = __hadd2(acc3.h[t], u7.h[t]);
            }
        }
        if (q < nq) {
            int4 sA = cs[q];
            H8 u0, u1, u2, u3;
            u0.f = g0h4[(size_t)sA.x * 8 + j3];
            u1.f = g0h4[(size_t)sA.y * 8 + j3];
            u2.f = g0h4[(size_t)sA.z * 8 + j3];
            u3.f = g0h4[(size_t)sA.w * 8 + j3];
            #pragma unroll
            for (int t = 0; t < 4; ++t) {
                acc0.h[t] = __hadd2(acc0.h[t], u0.h[t]);
                acc1.h[t] = __hadd2(acc1.h[t], u1.h[t]);
                acc2.h[t] = __hadd2(acc2.h[t], u2.h[t]);
                acc3.h[t] = __hadd2(acc3.h[t], u3.h[t]);
            }
        }
        __half2 dih = __float2half2_rn(di);
        #pragma unroll
        for (int t = 0; t < 4; ++t)
            acc0.h[t] = __hmul2(dih, __hadd2(__hadd2(acc0.h[t], acc1.h[t]),
                                             __hadd2(acc2.h[t], acc3.h[t])));
    }
    Hs4[node_l * 9 + j3] = acc0.f;
    __syncthreads();

    // MFMA MLP: 2 tiles of 16 rows; each wave does cols wave*16..+15, K=64.
    int wave = tid >> 6, lane = tid & 63;
    int m = lane & 15, quad = lane >> 4;
    int ncol = wave * 16 + m;
    F4H8 b0, b1;
    const float4* WT4 = (const float4*)wt;
    b0.f = WT4[ncol * 8 + quad];
    b1.f = WT4[ncol * 8 + 4 + quad];
    float bb_ = bias[ncol];
    #pragma unroll
    for (int t = 0; t < 2; ++t) {
        F4H8 a0, a1;
        a0.f = Hs4[(t * 16 + m) * 9 + quad];
        a1.f = Hs4[(t * 16 + m) * 9 + 4 + quad];
        float4_t acc = {0.f, 0.f, 0.f, 0.f};
        acc = __builtin_amdgcn_mfma_f32_16x16x32_f16(a0.h, b0.h, acc, 0, 0, 0);
        acc = __builtin_amdgcn_mfma_f32_16x16x32_f16(a1.h, b1.h, acc, 0, 0, 0);
        #pragma unroll
        for (int reg = 0; reg < 4; ++reg) {
            int row = t * 16 + quad * 4 + reg;
            int grow = row0 + row;
            if (grow < N) {
                float h = fmaxf(acc[reg] + bb_, 0.0f);
                g1h[(size_t)grow * DD + ncol] = __float2half(dvs[row] * h);
            }
        }
    }
}

// -------- layer 2 + pool: gather g1h, MFMA MLP, Wlin dot + segmented pool ---
__global__ __launch_bounds__(256, 8) void layer2_pool_kernel(
        const int2* __restrict__ rowinfo,
        const int* __restrict__ csr_src, const float2* __restrict__ xd,
        const float4* __restrict__ g1h4, const __half* __restrict__ wt,
        const float* __restrict__ bias, const int* __restrict__ batch,
        const float* __restrict__ Wlin, float* __restrict__ outacc, int N) {
    __shared__ float4 Hs4[32 * 9];       // padded stride 9
    __shared__ float lp0[128], lp1[128]; // [wave][row]
    __shared__ float p0s[32], p1s[32];
    __shared__ int   bat[32];
    int row0 = blockIdx.x * 32;
    int tid = threadIdx.x;
    int node_l = tid >> 3, j3 = tid & 7;
    int node = row0 + node_l;
    H8 acc0, acc1, acc2, acc3;
    acc0.f = make_float4(0.f, 0.f, 0.f, 0.f);
    acc1.f = acc0.f; acc2.f = acc0.f; acc3.f = acc0.f;
    if (node < N) {
        float di = xd[node].x;
        acc0.f = g1h4[(size_t)node * 8 + j3];   // self term, weight 1
        int2 ri = rowinfo[node];
        const int4* cs = (const int4*)(csr_src + ri.x);
        int nq = ri.y >> 2;
        int q = 0;
        for (; q + 1 < nq; q += 2) {
            int4 sA = cs[q], sB = cs[q + 1];
            H8 u0, u1, u2, u3, u4, u5, u6, u7;
            u0.f = g1h4[(size_t)sA.x * 8 + j3];
            u1.f = g1h4[(size_t)sA.y * 8 + j3];
            u2.f = g1h4[(size_t)sA.z * 8 + j3];
            u3.f = g1h4[(size_t)sA.w * 8 + j3];
            u4.f = g1h4[(size_t)sB.x * 8 + j3];
            u5.f = g1h4[(size_t)sB.y * 8 + j3];
            u6.f = g1h4[(size_t)sB.z * 8 + j3];
            u7.f = g1h4[(size_t)sB.w * 8 + j3];
            #pragma unroll
            for (int t = 0; t < 4; ++t) {
                acc0.h[t] = __hadd2(acc0.h[t], u0.h[t]);
                acc1.h[t] = __hadd2(acc1.h[t], u1.h[t]);
                acc2.h[t] = __hadd2(acc2.h[t], u2.h[t]);
                acc3.h[t] = __hadd2(acc3.h[t], u3.h[t]);
                acc0.h[t] = __hadd2(acc0.h[t], u4.h[t]);
                acc1.h[t] = __hadd2(acc1.h[t], u5.h[t]);
                acc2.h[t] = __hadd2(acc2.h[t], u6.h[t]);
                acc3.h[t] = __hadd2(acc3.h[t], u7.h[t]);
            }
        }
        if (q < nq) {
            int4 sA = cs[q];
            H8 u0, u1, u2, u3;
            u0.f = g1h4[(size_t)sA.x * 8 + j3];
            u1.f = g1h4[(size_t)sA.y * 8 + j3];
            u2.f = g1h4[(size_t)sA.z * 8 + j3];
            u3.f = g1h4[(size_t)sA.w * 8 + j3];
            #pragma unroll
            for (int t = 0; t < 4; ++t) {
                acc0.h[t] = __hadd2(acc0.h[t], u0.h[t]);
                acc1.h[t] = __hadd2(acc1.h[t], u1.h[t]);
                acc2.h[t] = __hadd2(acc2.h[t], u2.h[t]);
                acc3.h[t] = __hadd2(acc3.h[t], u3.h[t]);
            }
        }
        __half2 dih = __float2half2_rn(di);
        #pragma unroll
        for (int t = 0; t < 4; ++t)
            acc0.h[t] = __hmul2(dih, __hadd2(__hadd2(acc0.h[t], acc1.h[t]),
                                             __hadd2(acc2.h[t], acc3.h[t])));
    }
    Hs4[node_l * 9 + j3] = acc0.f;
    __syncthreads();

    int wave = tid >> 6, lane = tid & 63;
    int m = lane & 15, quad = lane >> 4;
    int ncol = wave * 16 + m;
    F4H8 b0, b1;
    const float4* WT4 = (const float4*)wt;
    b0.f = WT4[ncol * 8 + quad];
    b1.f = WT4[ncol * 8 + 4 + quad];
    float bb_  = bias[ncol];
    float wl0 = Wlin[ncol * 2 + 0];
    float wl1 = Wlin[ncol * 2 + 1];
    #pragma unroll
    for (int t = 0; t < 2; ++t) {
        F4H8 a0, a1;
        a0.f = Hs4[(t * 16 + m) * 9 + quad];
        a1.f = Hs4[(t * 16 + m) * 9 + 4 + quad];
        float4_t acc = {0.f, 0.f, 0.f, 0.f};
        acc = __builtin_amdgcn_mfma_f32_16x16x32_f16(a0.h, b0.h, acc, 0, 0, 0);
        acc = __builtin_amdgcn_mfma_f32_16x16x32_f16(a1.h, b1.h, acc, 0, 0, 0);
        #pragma unroll
        for (int reg = 0; reg < 4; ++reg) {
            int row = t * 16 + quad * 4 + reg;
            int grow = row0 + row;
            float h = (grow < N) ? fmaxf(acc[reg] + bb_, 0.0f) : 0.0f;
            float p0 = h * wl0;
            float p1 = h * wl1;
            #pragma unroll
            for (int off = 8; off >= 1; off >>= 1) {   // sum over 16 cols (m)
                p0 += __shfl_xor(p0, off);
                p1 += __shfl_xor(p1, off);
            }
            if (m == 0) {
                lp0[wave * 32 + row] = p0;
                lp1[wave * 32 + row] = p1;
            }
        }
    }
    __syncthreads();
    if (tid < 32) {
        int grow = row0 + tid;
        p0s[tid] = lp0[tid] + lp0[32 + tid] + lp0[64 + tid] + lp0[96 + tid];
        p1s[tid] = lp1[tid] + lp1[32 + tid] + lp1[64 + tid] + lp1[96 + tid];
        bat[tid] = (grow < N) ? batch[grow] : -1;
    }
    __syncthreads();
    if (tid < 32) {
        int bg = bat[tid];
        bool head = (bg >= 0) && (tid == 0 || bat[tid - 1] != bg);
        if (head) {
            float s0 = 0.f, s1 = 0.f;
            for (int k = tid; k < 32 && bat[k] == bg; ++k) {
                s0 += p0s[k];
                s1 += p1s[k];
            }
            atomAddF(&outacc[bg * 2 + 0], s0);
            atomAddF(&outacc[bg * 2 + 1], s1);
        }
    }
}

// counts via binary search on sorted batch; then divide + blin
__global__ void final_kernel(const float* __restrict__ outacc,
                             const int* __restrict__ batch,
                             const float* __restrict__ blin,
                             float* __restrict__ out, int G, int N) {
    int t = blockIdx.x * blockDim.x + threadIdx.x;
    if (t >= G * 2) return;
    int g = t >> 1, c = t & 1;
    int lo = 0, hi = N;
    while (lo < hi) { int m = (lo + hi) >> 1; if (batch[m] < g) lo = m + 1; else hi = m; }
    int lo2 = lo, hi2 = N;
    while (lo2 < hi2) { int m = (lo2 + hi2) >> 1; if (batch[m] < g + 1) lo2 = m + 1; else hi2 = m; }
    float cnt = (float)(lo2 - lo);
    out[t] = outacc[t] / fmaxf(cnt, 1.0f) + blin[c];
}

extern "C" void kernel_launch(void* const* d_in, const int* in_sizes, int n_in,
                              void* d_out, int out_size, void* d_ws, size_t ws_size,
                              hipStream_t stream) {
    const int*   x      = (const int*)d_in[0];
    const int*   ei     = (const int*)d_in[1];   // [2,E] row-major
    const int*   batch  = (const int*)d_in[3];
    const float* table  = (const float*)d_in[4];
    const float* W1     = (const float*)d_in[5];
    const float* b1     = (const float*)d_in[6];
    const float* W2     = (const float*)d_in[7];
    const float* b2     = (const float*)d_in[8];
    const float* Wlin   = (const float*)d_in[9];
    const float* blin   = (const float*)d_in[10];
    float* out = (float*)d_out;

    const int N = in_sizes[0];
    const int E = in_sizes[2];          // edge_type count == E
    const int G = out_size / 2;
    const int TBL = in_sizes[4];        // VOCAB*DD floats

    const int* src = ei;
    const int* dst = ei + E;

    const int K = (N + BKT - 1) / BKT;  // buckets
    const int M = NBLK * MAXK;          // (block, bucket) cells
    const int CH = (E + NBLK - 1) / NBLK;
    const int CSRSZ = E + SLACK * K + 64;

    // workspace layout (keep 16-B alignment for b128 reads)
    __half* g0h     = (__half*)d_ws;                      // (N+1)*64 halves
    __half* g1h     = g0h + (size_t)(N + 1) * DD;         // (N+1)*64 halves
    __half* th      = g1h + (size_t)(N + 1) * DD;         // TBL halves
    __half* w1t     = th + TBL;                           // 4096 halves
    __half* w2t     = w1t + DD * DD;                      // 4096 halves
    int*    pairbuf = (int*)(w2t + DD * DD);              // E ints
    int*    csr_src = pairbuf + E;                        // CSRSZ ints
    int2*   rowinfo = (int2*)(csr_src + CSRSZ);           // N int2
    float2* xd      = (float2*)(rowinfo + N);             // N+1 float2
    float*  outacc  = (float*)(xd + N + 1);               // 2G (zeroed in totals)
    int*    bb      = (int*)(outacc + 2 * G);             // K+1
    int*    bts     = bb + K + 1;                         // K
    int*    hist    = bts + K;                            // M
    int*    cur     = hist + M;                           // M

    const int BT = 256;

    // partition: per-chunk histogram -> wave-totals(+outacc zero) -> bucket
    //            scan -> per-bucket block scan -> append -> CSR sort
    bin_count_kernel<<<NBLK, BT, 0, stream>>>(dst, E, CH, hist, K,
                                              (const float2*)table,
                                              (__half2*)th, TBL / 2,
                                              W1, W2, w1t, w2t);
    totals_kernel<<<(K * 64 + BT - 1) / BT, BT, 0, stream>>>(hist, bts, outacc,
                                                             K, 2 * G);
    scan_bb_kernel<<<1, BT, 0, stream>>>(bts, bb, K, E);
    scanB_kernel<<<(K * 64 + BT - 1) / BT, BT, 0, stream>>>(hist, bb, cur, K);
    fill_kernel<<<NBLK, BT, 0, stream>>>(src, dst, E, CH, cur, pairbuf, K);
    build_csr_kernel<<<K, BT, 0, stream>>>(pairbuf, bb, x, rowinfo, xd,
                                           (const float4*)th, csr_src,
                                           g0h, g1h, N);

    // layer 1 (gather g0h + MFMA-MLP + relu; writes g1h = fp16(dinv*h1))
    int gRow = (N + 31) / 32;
    layer1_kernel<<<gRow, BT, 0, stream>>>(rowinfo, csr_src, xd,
                                           (const float4*)g0h, w1t, b1, g1h, N);
    // layer 2 (agg+MFMA-MLP+relu+pool fused)
    layer2_pool_kernel<<<gRow, BT, 0, stream>>>(rowinfo, csr_src, xd,
                                                (const float4*)g1h, w2t, b2,
                                                batch, Wlin, outacc, N);
    // final
    final_kernel<<<(G * 2 + BT - 1) / BT, BT, 0, stream>>>(outacc, batch, blin,
                                                           out, G, N);
}

// Round 17
// 236.895 us; speedup vs baseline: 1.1740x; 1.0486x over previous
//
#include <hip/hip_runtime.h>
#include <hip/hip_fp16.h>

// ---------------------------------------------------------------------------
// GCN forward on MI355X — round 17 (consolidation to best-of).
//  * Base = round 14 (measured 240.2 us): NBLK=256, layer1 gathers straight
//    from the L2-resident fp16 table (r15/r16's g0h materialization traded
//    1.25 MB L2-hot reads for 25.6 MB L3-cold ones + 8 us of build_csr
//    writes — net regression), 8-lane b128 fp16 gather, MFMA MLP, fused pool.
//  * Plus the one clean r16 win: wave-per-bucket totals_kernel (PER=4).
// ---------------------------------------------------------------------------

#define DD 64          // feature dim
#define BKT 256        // nodes per bucket (CSR build)
#define MAXK 1024      // max buckets; hist/cur row stride
#define NBLK 256       // partition blocks (chunks)
#define SLACK 772      // per-bucket csr slack: 3*256 pad + 4 alignment

typedef _Float16 half8_t __attribute__((ext_vector_type(8)));
typedef float float4_t __attribute__((ext_vector_type(4)));
union F4H8 { float4 f; half8_t h; };
union H8   { float4 f; __half2 h[4]; };

static __device__ __forceinline__ void atomAddF(float* p, float v) {
    unsafeAtomicAdd(p, v);   // global_atomic_add_f32 on gfx950
}

// ---- pass A: per-chunk histogram (+ fp16 conversions piggy-backed) --------
__global__ __launch_bounds__(256) void bin_count_kernel(
        const int* __restrict__ dst, int E, int CH,
        int* __restrict__ hist, int K,
        const float2* __restrict__ table2, __half2* __restrict__ th2, int n2,
        const float* __restrict__ W1, const float* __restrict__ W2,
        __half* __restrict__ w1t, __half* __restrict__ w2t) {
    __shared__ int lh[MAXK];
    int tid = threadIdx.x;
    for (int i = tid; i < K; i += 256) lh[i] = 0;
    __syncthreads();
    int stride = gridDim.x * 256;
    for (int i = blockIdx.x * 256 + tid; i < n2; i += stride)
        th2[i] = __float22half2_rn(table2[i]);
    for (int i = blockIdx.x * 256 + tid; i < DD * DD; i += stride) {
        int n = i >> 6, k = i & 63;
        w1t[i] = __float2half(W1[k * DD + n]);   // WT[n][k]
        w2t[i] = __float2half(W2[k * DD + n]);
    }
    int e0 = blockIdx.x * CH;
    int e1 = min(E, e0 + CH);
    for (int e = e0 + tid; e < e1; e += 256)
        atomicAdd(&lh[((unsigned)dst[e]) >> 8], 1);
    __syncthreads();
    for (int b = tid; b < K; b += 256)
        hist[blockIdx.x * MAXK + b] = lh[b];     // coalesced private row
}

// ---- pass B0: bucket totals, one WAVE per bucket; zero outacc -------------
__global__ __launch_bounds__(256) void totals_kernel(
        const int* __restrict__ hist, int* __restrict__ bts,
        float* __restrict__ outacc, int K, int G2) {
    int gt = blockIdx.x * 256 + threadIdx.x;
    if (gt < G2) outacc[gt] = 0.f;
    int wid = gt >> 6;            // wave id = bucket
    int lane = threadIdx.x & 63;
    if (wid >= K) return;
    const int PER = NBLK / 64;    // 4 cells per lane
    int s = 0;
    #pragma unroll
    for (int i = 0; i < PER; ++i)
        s += hist[(lane * PER + i) * MAXK + wid];
    #pragma unroll
    for (int off = 32; off >= 1; off >>= 1)
        s += __shfl_xor(s, off);
    if (lane == 0) bts[wid] = s;
}

// ---- pass B1: exclusive scan of bts[K] -> bb; bb[K] = E -------------------
__global__ __launch_bounds__(256) void scan_bb_kernel(
        const int* __restrict__ bts, int* __restrict__ bb, int K, int E) {
    __shared__ int part[256];
    int tid = threadIdx.x;
    int CH2 = (K + 255) / 256;
    int base = tid * CH2;
    int s = 0;
    for (int i = 0; i < CH2; ++i) {
        int idx = base + i;
        if (idx < K) s += bts[idx];
    }
    part[tid] = s;
    __syncthreads();
    if (tid < 64) {
        int carry = 0;
        for (int c = 0; c < 4; ++c) {
            int orig = part[c * 64 + tid];
            int v = orig;
            #pragma unroll
            for (int off = 1; off < 64; off <<= 1) {
                int t = __shfl_up(v, off);
                if (tid >= off) v += t;
            }
            int tot = __shfl(v, 63);
            part[c * 64 + tid] = v - orig + carry;   // exclusive
            carry += tot;
        }
    }
    __syncthreads();
    int run = part[tid];
    for (int i = 0; i < CH2; ++i) {
        int idx = base + i;
        if (idx < K) {
            bb[idx] = run;
            run += bts[idx];
        }
    }
    if (tid == 0) bb[K] = E;
}

// ---- pass B2: one WAVE per bucket scans across blocks -> cur[blk][bucket] -
__global__ __launch_bounds__(256) void scanB_kernel(
        const int* __restrict__ hist, const int* __restrict__ bb,
        int* __restrict__ cur, int K) {
    int wid = (blockIdx.x * 256 + threadIdx.x) >> 6;   // global wave id = bucket
    int lane = threadIdx.x & 63;
    if (wid >= K) return;
    int b = wid;
    const int PER = NBLK / 64;    // 4 blocks per lane
    int v[PER];
    int sum = 0;
    #pragma unroll
    for (int i = 0; i < PER; ++i) {
        v[i] = hist[(lane * PER + i) * MAXK + b];
        sum += v[i];
    }
    int pref = sum;
    #pragma unroll
    for (int off = 1; off < 64; off <<= 1) {
        int t = __shfl_up(pref, off);
        if (lane >= off) pref += t;
    }
    int run = bb[b] + pref - sum;   // exclusive
    #pragma unroll
    for (int i = 0; i < PER; ++i) {
        cur[(lane * PER + i) * MAXK + b] = run;
        run += v[i];
    }
}

// ---- pass C: append packed pairs; cursors in LDS (block-private cells) ----
__global__ __launch_bounds__(256) void fill_kernel(
        const int* __restrict__ src, const int* __restrict__ dst, int E, int CH,
        const int* __restrict__ cur, int* __restrict__ pairbuf, int K) {
    __shared__ int lcur[MAXK];
    int tid = threadIdx.x;
    for (int b = tid; b < K; b += 256)
        lcur[b] = cur[blockIdx.x * MAXK + b];
    __syncthreads();
    int e0 = blockIdx.x * CH;
    int e1 = min(E, e0 + CH);
    for (int e = e0 + tid; e < e1; e += 256) {
        int s = src[e], d = dst[e];
        int pos = atomicAdd(&lcur[((unsigned)d) >> 8], 1);
        pairbuf[pos] = s | ((d & 255) << 24);
    }
}

// ---- pass D: per-bucket padded CSR build + rowinfo/xd (coalesced) ---------
__global__ __launch_bounds__(256) void build_csr_kernel(
        const int* __restrict__ pairbuf, const int* __restrict__ bnd,
        const int* __restrict__ x, int2* __restrict__ rowinfo,
        float2* __restrict__ xd,
        int* __restrict__ csr_src, __half* __restrict__ g1h, int N) {
    __shared__ int cnt[256], basel[256], curl[256];
    int tid = threadIdx.x;
    int b = blockIdx.x;
    int node0 = b << 8;
    cnt[tid] = 0;
    __syncthreads();
    int bb0 = bnd[b], bb1 = bnd[b + 1];
    for (int i = bb0 + tid; i < bb1; i += 256)
        atomicAdd(&cnt[((unsigned)pairbuf[i]) >> 24], 1);
    __syncthreads();
    int c  = cnt[tid];
    int pc = (c + 3) & ~3;              // padded count
    {
        __syncthreads();
        basel[tid] = pc;
        __syncthreads();
        if (tid < 64) {
            int carry = 0;
            for (int cc = 0; cc < 4; ++cc) {
                int orig = basel[cc * 64 + tid];
                int v = orig;
                #pragma unroll
                for (int off = 1; off < 64; off <<= 1) {
                    int t = __shfl_up(v, off);
                    if (tid >= off) v += t;
                }
                int tot = __shfl(v, 63);
                cnt[cc * 64 + tid] = v - orig + carry;   // exclusive
                carry += tot;
            }
        }
        __syncthreads();
    }
    int cb0 = ((bb0 + 3) & ~3) + SLACK * b;   // aligned csr base for bucket
    int node = node0 + tid;
    int myBase = cb0 + cnt[tid];
    curl[tid] = myBase;
    if (node < N) {
        rowinfo[node] = make_int2(myBase, pc);
        xd[node] = make_float2(rsqrtf((float)c + 1.0f), __int_as_float(x[node]));
        for (int t = c; t < pc; ++t) csr_src[myBase + t] = N;   // sentinel pad
    } else if (node == N) {
        xd[N] = make_float2(0.0f, __int_as_float(0));           // zero weight
        float2* z = (float2*)(g1h + (size_t)N * DD);            // zero row N
        for (int t = 0; t < DD / 4; ++t) z[t] = make_float2(0.f, 0.f);
    }
    __syncthreads();
    for (int i = bb0 + tid; i < bb1; i += 256) {
        int pk = pairbuf[i];
        int pos = atomicAdd(&curl[((unsigned)pk) >> 24], 1);
        csr_src[pos] = pk & 0x00FFFFFF;
    }
}

// ---------------- layer 1: agg from fp16 table, MFMA MLP, g1h = f16(dv*h1) --
// 8 lanes/node, b128 chunks; unroll x2; Hs stride 9 (bank-conflict pad).
__global__ __launch_bounds__(256, 8) void layer1_kernel(
        const int2* __restrict__ rowinfo,
        const int* __restrict__ csr_src, const float2* __restrict__ xd,
        const float4* __restrict__ th4, const __half* __restrict__ wt,
        const float* __restrict__ bias, __half* __restrict__ g1h, int N) {
    __shared__ float4 Hs4[32 * 9];   // padded stride 9
    __shared__ float dvs[32];
    int row0 = blockIdx.x * 32;
    int tid = threadIdx.x;
    int node_l = tid >> 3, j3 = tid & 7;
    int node = row0 + node_l;
    H8 acc0, acc1, acc2, acc3;
    acc0.f = make_float4(0.f, 0.f, 0.f, 0.f);
    acc1.f = acc0.f; acc2.f = acc0.f; acc3.f = acc0.f;
    __half2 dh = __float2half2_rn(0.f);
    if (node < N) {
        float2 sxd = xd[node];
        float di = sxd.x;
        if (j3 == 0) dvs[node_l] = di;
        dh = __float2half2_rn(di);
        H8 tv; tv.f = th4[(size_t)__float_as_int(sxd.y) * 8 + j3];
        acc0.h[0] = __hmul2(dh, tv.h[0]); acc0.h[1] = __hmul2(dh, tv.h[1]);
        acc0.h[2] = __hmul2(dh, tv.h[2]); acc0.h[3] = __hmul2(dh, tv.h[3]);
        int2 ri = rowinfo[node];
        const int4* cs = (const int4*)(csr_src + ri.x);
        int nq = ri.y >> 2;
        int q = 0;
        for (; q + 1 < nq; q += 2) {
            int4 sA = cs[q], sB = cs[q + 1];
            float2 pa = xd[sA.x], pb = xd[sA.y], pc_ = xd[sA.z], pd = xd[sA.w];
            float2 pe = xd[sB.x], pf = xd[sB.y], pg = xd[sB.z], ph = xd[sB.w];
            H8 u0, u1, u2, u3, u4, u5, u6, u7;
            u0.f = th4[(size_t)__float_as_int(pa.y)  * 8 + j3];
            u1.f = th4[(size_t)__float_as_int(pb.y)  * 8 + j3];
            u2.f = th4[(size_t)__float_as_int(pc_.y) * 8 + j3];
            u3.f = th4[(size_t)__float_as_int(pd.y)  * 8 + j3];
            u4.f = th4[(size_t)__float_as_int(pe.y)  * 8 + j3];
            u5.f = th4[(size_t)__float_as_int(pf.y)  * 8 + j3];
            u6.f = th4[(size_t)__float_as_int(pg.y)  * 8 + j3];
            u7.f = th4[(size_t)__float_as_int(ph.y)  * 8 + j3];
            __half2 w0 = __float2half2_rn(pa.x), w1 = __float2half2_rn(pb.x);
            __half2 w2 = __float2half2_rn(pc_.x), w3 = __float2half2_rn(pd.x);
            __half2 w4 = __float2half2_rn(pe.x), w5 = __float2half2_rn(pf.x);
            __half2 w6 = __float2half2_rn(pg.x), w7 = __float2half2_rn(ph.x);
            #pragma unroll
            for (int t = 0; t < 4; ++t) {
                acc0.h[t] = __hfma2(w0, u0.h[t], acc0.h[t]);
                acc1.h[t] = __hfma2(w1, u1.h[t], acc1.h[t]);
                acc2.h[t] = __hfma2(w2, u2.h[t], acc2.h[t]);
                acc3.h[t] = __hfma2(w3, u3.h[t], acc3.h[t]);
                acc0.h[t] = __hfma2(w4, u4.h[t], acc0.h[t]);
                acc1.h[t] = __hfma2(w5, u5.h[t], acc1.h[t]);
                acc2.h[t] = __hfma2(w6, u6.h[t], acc2.h[t]);
                acc3.h[t] = __hfma2(w7, u7.h[t], acc3.h[t]);
            }
        }
        if (q < nq) {
            int4 sA = cs[q];
            float2 pa = xd[sA.x], pb = xd[sA.y], pc_ = xd[sA.z], pd = xd[sA.w];
            H8 u0, u1, u2, u3;
            u0.f = th4[(size_t)__float_as_int(pa.y)  * 8 + j3];
            u1.f = th4[(size_t)__float_as_int(pb.y)  * 8 + j3];
            u2.f = th4[(size_t)__float_as_int(pc_.y) * 8 + j3];
            u3.f = th4[(size_t)__float_as_int(pd.y)  * 8 + j3];
            __half2 w0 = __float2half2_rn(pa.x), w1 = __float2half2_rn(pb.x);
            __half2 w2 = __float2half2_rn(pc_.x), w3 = __float2half2_rn(pd.x);
            #pragma unroll
            for (int t = 0; t < 4; ++t) {
                acc0.h[t] = __hfma2(w0, u0.h[t], acc0.h[t]);
                acc1.h[t] = __hfma2(w1, u1.h[t], acc1.h[t]);
                acc2.h[t] = __hfma2(w2, u2.h[t], acc2.h[t]);
                acc3.h[t] = __hfma2(w3, u3.h[t], acc3.h[t]);
            }
        }
        #pragma unroll
        for (int t = 0; t < 4; ++t)
            acc0.h[t] = __hmul2(dh, __hadd2(__hadd2(acc0.h[t], acc1.h[t]),
                                            __hadd2(acc2.h[t], acc3.h[t])));
    }
    Hs4[node_l * 9 + j3] = acc0.f;
    __syncthreads();

    // MFMA MLP: 2 tiles of 16 rows; each wave does cols wave*16..+15, K=64.
    int wave = tid >> 6, lane = tid & 63;
    int m = lane & 15, quad = lane >> 4;
    int ncol = wave * 16 + m;
    F4H8 b0, b1;
    const float4* WT4 = (const float4*)wt;
    b0.f = WT4[ncol * 8 + quad];
    b1.f = WT4[ncol * 8 + 4 + quad];
    float bb_ = bias[ncol];
    #pragma unroll
    for (int t = 0; t < 2; ++t) {
        F4H8 a0, a1;
        a0.f = Hs4[(t * 16 + m) * 9 + quad];
        a1.f = Hs4[(t * 16 + m) * 9 + 4 + quad];
        float4_t acc = {0.f, 0.f, 0.f, 0.f};
        acc = __builtin_amdgcn_mfma_f32_16x16x32_f16(a0.h, b0.h, acc, 0, 0, 0);
        acc = __builtin_amdgcn_mfma_f32_16x16x32_f16(a1.h, b1.h, acc, 0, 0, 0);
        #pragma unroll
        for (int reg = 0; reg < 4; ++reg) {
            int row = t * 16 + quad * 4 + reg;
            int grow = row0 + row;
            if (grow < N) {
                float h = fmaxf(acc[reg] + bb_, 0.0f);
                g1h[(size_t)grow * DD + ncol] = __float2half(dvs[row] * h);
            }
        }
    }
}

// -------- layer 2 + pool: gather g1h, MFMA MLP, Wlin dot + segmented pool ---
__global__ __launch_bounds__(256, 8) void layer2_pool_kernel(
        const int2* __restrict__ rowinfo,
        const int* __restrict__ csr_src, const float2* __restrict__ xd,
        const float4* __restrict__ g1h4, const __half* __restrict__ wt,
        const float* __restrict__ bias, const int* __restrict__ batch,
        const float* __restrict__ Wlin, float* __restrict__ outacc, int N) {
    __shared__ float4 Hs4[32 * 9];       // padded stride 9
    __shared__ float lp0[128], lp1[128]; // [wave][row]
    __shared__ float p0s[32], p1s[32];
    __shared__ int   bat[32];
    int row0 = blockIdx.x * 32;
    int tid = threadIdx.x;
    int node_l = tid >> 3, j3 = tid & 7;
    int node = row0 + node_l;
    H8 acc0, acc1, acc2, acc3;
    acc0.f = make_float4(0.f, 0.f, 0.f, 0.f);
    acc1.f = acc0.f; acc2.f = acc0.f; acc3.f = acc0.f;
    if (node < N) {
        float di = xd[node].x;
        acc0.f = g1h4[(size_t)node * 8 + j3];   // self term, weight 1
        int2 ri = rowinfo[node];
        const int4* cs = (const int4*)(csr_src + ri.x);
        int nq = ri.y >> 2;
        int q = 0;
        for (; q + 1 < nq; q += 2) {
            int4 sA = cs[q], sB = cs[q + 1];
            H8 u0, u1, u2, u3, u4, u5, u6, u7;
            u0.f = g1h4[(size_t)sA.x * 8 + j3];
            u1.f = g1h4[(size_t)sA.y * 8 + j3];
            u2.f = g1h4[(size_t)sA.z * 8 + j3];
            u3.f = g1h4[(size_t)sA.w * 8 + j3];
            u4.f = g1h4[(size_t)sB.x * 8 + j3];
            u5.f = g1h4[(size_t)sB.y * 8 + j3];
            u6.f = g1h4[(size_t)sB.z * 8 + j3];
            u7.f = g1h4[(size_t)sB.w * 8 + j3];
            #pragma unroll
            for (int t = 0; t < 4; ++t) {
                acc0.h[t] = __hadd2(acc0.h[t], u0.h[t]);
                acc1.h[t] = __hadd2(acc1.h[t], u1.h[t]);
                acc2.h[t] = __hadd2(acc2.h[t], u2.h[t]);
                acc3.h[t] = __hadd2(acc3.h[t], u3.h[t]);
                acc0.h[t] = __hadd2(acc0.h[t], u4.h[t]);
                acc1.h[t] = __hadd2(acc1.h[t], u5.h[t]);
                acc2.h[t] = __hadd2(acc2.h[t], u6.h[t]);
                acc3.h[t] = __hadd2(acc3.h[t], u7.h[t]);
            }
        }
        if (q < nq) {
            int4 sA = cs[q];
            H8 u0, u1, u2, u3;
            u0.f = g1h4[(size_t)sA.x * 8 + j3];
            u1.f = g1h4[(size_t)sA.y * 8 + j3];
            u2.f = g1h4[(size_t)sA.z * 8 + j3];
            u3.f = g1h4[(size_t)sA.w * 8 + j3];
            #pragma unroll
            for (int t = 0; t < 4; ++t) {
                acc0.h[t] = __hadd2(acc0.h[t], u0.h[t]);
                acc1.h[t] = __hadd2(acc1.h[t], u1.h[t]);
                acc2.h[t] = __hadd2(acc2.h[t], u2.h[t]);
                acc3.h[t] = __hadd2(acc3.h[t], u3.h[t]);
            }
        }
        __half2 dih = __float2half2_rn(di);
        #pragma unroll
        for (int t = 0; t < 4; ++t)
            acc0.h[t] = __hmul2(dih, __hadd2(__hadd2(acc0.h[t], acc1.h[t]),
                                             __hadd2(acc2.h[t], acc3.h[t])));
    }
    Hs4[node_l * 9 + j3] = acc0.f;
    __syncthreads();

    int wave = tid >> 6, lane = tid & 63;
    int m = lane & 15, quad = lane >> 4;
    int ncol = wave * 16 + m;
    F4H8 b0, b1;
    const float4* WT4 = (const float4*)wt;
    b0.f = WT4[ncol * 8 + quad];
    b1.f = WT4[ncol * 8 + 4 + quad];
    float bb_  = bias[ncol];
    float wl0 = Wlin[ncol * 2 + 0];
    float wl1 = Wlin[ncol * 2 + 1];
    #pragma unroll
    for (int t = 0; t < 2; ++t) {
        F4H8 a0, a1;
        a0.f = Hs4[(t * 16 + m) * 9 + quad];
        a1.f = Hs4[(t * 16 + m) * 9 + 4 + quad];
        float4_t acc = {0.f, 0.f, 0.f, 0.f};
        acc = __builtin_amdgcn_mfma_f32_16x16x32_f16(a0.h, b0.h, acc, 0, 0, 0);
        acc = __builtin_amdgcn_mfma_f32_16x16x32_f16(a1.h, b1.h, acc, 0, 0, 0);
        #pragma unroll
        for (int reg = 0; reg < 4; ++reg) {
            int row = t * 16 + quad * 4 + reg;
            int grow = row0 + row;
            float h = (grow < N) ? fmaxf(acc[reg] + bb_, 0.0f) : 0.0f;
            float p0 = h * wl0;
            float p1 = h * wl1;
            #pragma unroll
            for (int off = 8; off >= 1; off >>= 1) {   // sum over 16 cols (m)
                p0 += __shfl_xor(p0, off);
                p1 += __shfl_xor(p1, off);
            }
            if (m == 0) {
                lp0[wave * 32 + row] = p0;
                lp1[wave * 32 + row] = p1;
            }
        }
    }
    __syncthreads();
    if (tid < 32) {
        int grow = row0 + tid;
        p0s[tid] = lp0[tid] + lp0[32 + tid] + lp0[64 + tid] + lp0[96 + tid];
        p1s[tid] = lp1[tid] + lp1[32 + tid] + lp1[64 + tid] + lp1[96 + tid];
        bat[tid] = (grow < N) ? batch[grow] : -1;
    }
    __syncthreads();
    if (tid < 32) {
        int bg = bat[tid];
        bool head = (bg >= 0) && (tid == 0 || bat[tid - 1] != bg);
        if (head) {
            float s0 = 0.f, s1 = 0.f;
            for (int k = tid; k < 32 && bat[k] == bg; ++k) {
                s0 += p0s[k];
                s1 += p1s[k];
            }
            atomAddF(&outacc[bg * 2 + 0], s0);
            atomAddF(&outacc[bg * 2 + 1], s1);
        }
    }
}

// counts via binary search on sorted batch; then divide + blin
__global__ void final_kernel(const float* __restrict__ outacc,
                             const int* __restrict__ batch,
                             const float* __restrict__ blin,
                             float* __restrict__ out, int G, int N) {
    int t = blockIdx.x * blockDim.x + threadIdx.x;
    if (t >= G * 2) return;
    int g = t >> 1, c = t & 1;
    int lo = 0, hi = N;
    while (lo < hi) { int m = (lo + hi) >> 1; if (batch[m] < g) lo = m + 1; else hi = m; }
    int lo2 = lo, hi2 = N;
    while (lo2 < hi2) { int m = (lo2 + hi2) >> 1; if (batch[m] < g + 1) lo2 = m + 1; else hi2 = m; }
    float cnt = (float)(lo2 - lo);
    out[t] = outacc[t] / fmaxf(cnt, 1.0f) + blin[c];
}

extern "C" void kernel_launch(void* const* d_in, const int* in_sizes, int n_in,
                              void* d_out, int out_size, void* d_ws, size_t ws_size,
                              hipStream_t stream) {
    const int*   x      = (const int*)d_in[0];
    const int*   ei     = (const int*)d_in[1];   // [2,E] row-major
    const int*   batch  = (const int*)d_in[3];
    const float* table  = (const float*)d_in[4];
    const float* W1     = (const float*)d_in[5];
    const float* b1     = (const float*)d_in[6];
    const float* W2     = (const float*)d_in[7];
    const float* b2     = (const float*)d_in[8];
    const float* Wlin   = (const float*)d_in[9];
    const float* blin   = (const float*)d_in[10];
    float* out = (float*)d_out;

    const int N = in_sizes[0];
    const int E = in_sizes[2];          // edge_type count == E
    const int G = out_size / 2;
    const int TBL = in_sizes[4];        // VOCAB*DD floats

    const int* src = ei;
    const int* dst = ei + E;

    const int K = (N + BKT - 1) / BKT;  // buckets
    const int M = NBLK * MAXK;          // (block, bucket) cells
    const int CH = (E + NBLK - 1) / NBLK;
    const int CSRSZ = E + SLACK * K + 64;

    // workspace layout (keep 16-B alignment for b128 reads)
    __half* g1h     = (__half*)d_ws;                      // (N+1)*64 halves
    __half* th      = g1h + (size_t)(N + 1) * DD;         // TBL halves
    __half* w1t     = th + TBL;                           // 4096 halves
    __half* w2t     = w1t + DD * DD;                      // 4096 halves
    int*    pairbuf = (int*)(w2t + DD * DD);              // E ints
    int*    csr_src = pairbuf + E;                        // CSRSZ ints
    int2*   rowinfo = (int2*)(csr_src + CSRSZ);           // N int2
    float2* xd      = (float2*)(rowinfo + N);             // N+1 float2
    float*  outacc  = (float*)(xd + N + 1);               // 2G (zeroed in totals)
    int*    bb      = (int*)(outacc + 2 * G);             // K+1
    int*    bts     = bb + K + 1;                         // K
    int*    hist    = bts + K;                            // M
    int*    cur     = hist + M;                           // M

    const int BT = 256;

    // partition: per-chunk histogram -> wave-totals(+outacc zero) -> bucket
    //            scan -> per-bucket block scan -> append -> CSR sort
    bin_count_kernel<<<NBLK, BT, 0, stream>>>(dst, E, CH, hist, K,
                                              (const float2*)table,
                                              (__half2*)th, TBL / 2,
                                              W1, W2, w1t, w2t);
    totals_kernel<<<(K * 64 + BT - 1) / BT, BT, 0, stream>>>(hist, bts, outacc,
                                                             K, 2 * G);
    scan_bb_kernel<<<1, BT, 0, stream>>>(bts, bb, K, E);
    scanB_kernel<<<(K * 64 + BT - 1) / BT, BT, 0, stream>>>(hist, bb, cur, K);
    fill_kernel<<<NBLK, BT, 0, stream>>>(src, dst, E, CH, cur, pairbuf, K);
    build_csr_kernel<<<K, BT, 0, stream>>>(pairbuf, bb, x, rowinfo, xd,
                                           csr_src, g1h, N);

    // layer 1 (embed+agg+MFMA-MLP+relu fused; writes g1h = fp16(dinv*h1))
    int gRow = (N + 31) / 32;
    layer1_kernel<<<gRow, BT, 0, stream>>>(rowinfo, csr_src, xd,
                                           (const float4*)th, w1t, b1, g1h, N);
    // layer 2 (agg+MFMA-MLP+relu+pool fused)
    layer2_pool_kernel<<<gRow, BT, 0, stream>>>(rowinfo, csr_src, xd,
                                                (const float4*)g1h, w2t, b2,
                                                batch, Wlin, outacc, N);
    // final
    final_kernel<<<(G * 2 + BT - 1) / BT, BT, 0, stream>>>(outacc, batch, blin,
                                                           out, G, N);
}

// Round 18
// 225.487 us; speedup vs baseline: 1.2334x; 1.0506x over previous
//
#include <hip/hip_runtime.h>
#include <hip/hip_fp16.h>

// ---------------------------------------------------------------------------
// GCN forward on MI355X — round 18.
//  * bin_count / fill at 1024 threads/block (same 256 blocks & cell layout):
//    they ran 1 block/CU x 4 waves = 12.5% occupancy; block size was never
//    decoupled from the LDS-cursor cell design.  Now 16 waves/CU for the two
//    per-edge passes.
//  * Everything else identical to round 17 (measured 236.9 us).
// ---------------------------------------------------------------------------

#define DD 64          // feature dim
#define BKT 256        // nodes per bucket (CSR build)
#define MAXK 1024      // max buckets; hist/cur row stride
#define NBLK 256       // partition blocks (chunks)
#define SLACK 772      // per-bucket csr slack: 3*256 pad + 4 alignment
#define BTE 1024       // threads/block for per-edge passes

typedef _Float16 half8_t __attribute__((ext_vector_type(8)));
typedef float float4_t __attribute__((ext_vector_type(4)));
union F4H8 { float4 f; half8_t h; };
union H8   { float4 f; __half2 h[4]; };

static __device__ __forceinline__ void atomAddF(float* p, float v) {
    unsafeAtomicAdd(p, v);   // global_atomic_add_f32 on gfx950
}

// ---- pass A: per-chunk histogram (+ fp16 conversions piggy-backed) --------
__global__ __launch_bounds__(BTE) void bin_count_kernel(
        const int* __restrict__ dst, int E, int CH,
        int* __restrict__ hist, int K,
        const float2* __restrict__ table2, __half2* __restrict__ th2, int n2,
        const float* __restrict__ W1, const float* __restrict__ W2,
        __half* __restrict__ w1t, __half* __restrict__ w2t) {
    __shared__ int lh[MAXK];
    int tid = threadIdx.x;
    for (int i = tid; i < K; i += BTE) lh[i] = 0;
    __syncthreads();
    int stride = gridDim.x * BTE;
    for (int i = blockIdx.x * BTE + tid; i < n2; i += stride)
        th2[i] = __float22half2_rn(table2[i]);
    for (int i = blockIdx.x * BTE + tid; i < DD * DD; i += stride) {
        int n = i >> 6, k = i & 63;
        w1t[i] = __float2half(W1[k * DD + n]);   // WT[n][k]
        w2t[i] = __float2half(W2[k * DD + n]);
    }
    int e0 = blockIdx.x * CH;
    int e1 = min(E, e0 + CH);
    for (int e = e0 + tid; e < e1; e += BTE)
        atomicAdd(&lh[((unsigned)dst[e]) >> 8], 1);
    __syncthreads();
    for (int b = tid; b < K; b += BTE)
        hist[blockIdx.x * MAXK + b] = lh[b];     // coalesced private row
}

// ---- pass B0: bucket totals, one WAVE per bucket; zero outacc -------------
__global__ __launch_bounds__(256) void totals_kernel(
        const int* __restrict__ hist, int* __restrict__ bts,
        float* __restrict__ outacc, int K, int G2) {
    int gt = blockIdx.x * 256 + threadIdx.x;
    if (gt < G2) outacc[gt] = 0.f;
    int wid = gt >> 6;            // wave id = bucket
    int lane = threadIdx.x & 63;
    if (wid >= K) return;
    const int PER = NBLK / 64;    // 4 cells per lane
    int s = 0;
    #pragma unroll
    for (int i = 0; i < PER; ++i)
        s += hist[(lane * PER + i) * MAXK + wid];
    #pragma unroll
    for (int off = 32; off >= 1; off >>= 1)
        s += __shfl_xor(s, off);
    if (lane == 0) bts[wid] = s;
}

// ---- pass B1: exclusive scan of bts[K] -> bb; bb[K] = E -------------------
__global__ __launch_bounds__(256) void scan_bb_kernel(
        const int* __restrict__ bts, int* __restrict__ bb, int K, int E) {
    __shared__ int part[256];
    int tid = threadIdx.x;
    int CH2 = (K + 255) / 256;
    int base = tid * CH2;
    int s = 0;
    for (int i = 0; i < CH2; ++i) {
        int idx = base + i;
        if (idx < K) s += bts[idx];
    }
    part[tid] = s;
    __syncthreads();
    if (tid < 64) {
        int carry = 0;
        for (int c = 0; c < 4; ++c) {
            int orig = part[c * 64 + tid];
            int v = orig;
            #pragma unroll
            for (int off = 1; off < 64; off <<= 1) {
                int t = __shfl_up(v, off);
                if (tid >= off) v += t;
            }
            int tot = __shfl(v, 63);
            part[c * 64 + tid] = v - orig + carry;   // exclusive
            carry += tot;
        }
    }
    __syncthreads();
    int run = part[tid];
    for (int i = 0; i < CH2; ++i) {
        int idx = base + i;
        if (idx < K) {
            bb[idx] = run;
            run += bts[idx];
        }
    }
    if (tid == 0) bb[K] = E;
}

// ---- pass B2: one WAVE per bucket scans across blocks -> cur[blk][bucket] -
__global__ __launch_bounds__(256) void scanB_kernel(
        const int* __restrict__ hist, const int* __restrict__ bb,
        int* __restrict__ cur, int K) {
    int wid = (blockIdx.x * 256 + threadIdx.x) >> 6;   // global wave id = bucket
    int lane = threadIdx.x & 63;
    if (wid >= K) return;
    int b = wid;
    const int PER = NBLK / 64;    // 4 blocks per lane
    int v[PER];
    int sum = 0;
    #pragma unroll
    for (int i = 0; i < PER; ++i) {
        v[i] = hist[(lane * PER + i) * MAXK + b];
        sum += v[i];
    }
    int pref = sum;
    #pragma unroll
    for (int off = 1; off < 64; off <<= 1) {
        int t = __shfl_up(pref, off);
        if (lane >= off) pref += t;
    }
    int run = bb[b] + pref - sum;   // exclusive
    #pragma unroll
    for (int i = 0; i < PER; ++i) {
        cur[(lane * PER + i) * MAXK + b] = run;
        run += v[i];
    }
}

// ---- pass C: append packed pairs; cursors in LDS (block-private cells) ----
__global__ __launch_bounds__(BTE) void fill_kernel(
        const int* __restrict__ src, const int* __restrict__ dst, int E, int CH,
        const int* __restrict__ cur, int* __restrict__ pairbuf, int K) {
    __shared__ int lcur[MAXK];
    int tid = threadIdx.x;
    for (int b = tid; b < K; b += BTE)
        lcur[b] = cur[blockIdx.x * MAXK + b];
    __syncthreads();
    int e0 = blockIdx.x * CH;
    int e1 = min(E, e0 + CH);
    for (int e = e0 + tid; e < e1; e += BTE) {
        int s = src[e], d = dst[e];
        int pos = atomicAdd(&lcur[((unsigned)d) >> 8], 1);
        pairbuf[pos] = s | ((d & 255) << 24);
    }
}

// ---- pass D: per-bucket padded CSR build + rowinfo/xd (coalesced) ---------
__global__ __launch_bounds__(256) void build_csr_kernel(
        const int* __restrict__ pairbuf, const int* __restrict__ bnd,
        const int* __restrict__ x, int2* __restrict__ rowinfo,
        float2* __restrict__ xd,
        int* __restrict__ csr_src, __half* __restrict__ g1h, int N) {
    __shared__ int cnt[256], basel[256], curl[256];
    int tid = threadIdx.x;
    int b = blockIdx.x;
    int node0 = b << 8;
    cnt[tid] = 0;
    __syncthreads();
    int bb0 = bnd[b], bb1 = bnd[b + 1];
    for (int i = bb0 + tid; i < bb1; i += 256)
        atomicAdd(&cnt[((unsigned)pairbuf[i]) >> 24], 1);
    __syncthreads();
    int c  = cnt[tid];
    int pc = (c + 3) & ~3;              // padded count
    {
        __syncthreads();
        basel[tid] = pc;
        __syncthreads();
        if (tid < 64) {
            int carry = 0;
            for (int cc = 0; cc < 4; ++cc) {
                int orig = basel[cc * 64 + tid];
                int v = orig;
                #pragma unroll
                for (int off = 1; off < 64; off <<= 1) {
                    int t = __shfl_up(v, off);
                    if (tid >= off) v += t;
                }
                int tot = __shfl(v, 63);
                cnt[cc * 64 + tid] = v - orig + carry;   // exclusive
                carry += tot;
            }
        }
        __syncthreads();
    }
    int cb0 = ((bb0 + 3) & ~3) + SLACK * b;   // aligned csr base for bucket
    int node = node0 + tid;
    int myBase = cb0 + cnt[tid];
    curl[tid] = myBase;
    if (node < N) {
        rowinfo[node] = make_int2(myBase, pc);
        xd[node] = make_float2(rsqrtf((float)c + 1.0f), __int_as_float(x[node]));
        for (int t = c; t < pc; ++t) csr_src[myBase + t] = N;   // sentinel pad
    } else if (node == N) {
        xd[N] = make_float2(0.0f, __int_as_float(0));           // zero weight
        float2* z = (float2*)(g1h + (size_t)N * DD);            // zero row N
        for (int t = 0; t < DD / 4; ++t) z[t] = make_float2(0.f, 0.f);
    }
    __syncthreads();
    for (int i = bb0 + tid; i < bb1; i += 256) {
        int pk = pairbuf[i];
        int pos = atomicAdd(&curl[((unsigned)pk) >> 24], 1);
        csr_src[pos] = pk & 0x00FFFFFF;
    }
}

// ---------------- layer 1: agg from fp16 table, MFMA MLP, g1h = f16(dv*h1) --
// 8 lanes/node, b128 chunks; unroll x2; Hs stride 9 (bank-conflict pad).
__global__ __launch_bounds__(256, 8) void layer1_kernel(
        const int2* __restrict__ rowinfo,
        const int* __restrict__ csr_src, const float2* __restrict__ xd,
        const float4* __restrict__ th4, const __half* __restrict__ wt,
        const float* __restrict__ bias, __half* __restrict__ g1h, int N) {
    __shared__ float4 Hs4[32 * 9];   // padded stride 9
    __shared__ float dvs[32];
    int row0 = blockIdx.x * 32;
    int tid = threadIdx.x;
    int node_l = tid >> 3, j3 = tid & 7;
    int node = row0 + node_l;
    H8 acc0, acc1, acc2, acc3;
    acc0.f = make_float4(0.f, 0.f, 0.f, 0.f);
    acc1.f = acc0.f; acc2.f = acc0.f; acc3.f = acc0.f;
    __half2 dh = __float2half2_rn(0.f);
    if (node < N) {
        float2 sxd = xd[node];
        float di = sxd.x;
        if (j3 == 0) dvs[node_l] = di;
        dh = __float2half2_rn(di);
        H8 tv; tv.f = th4[(size_t)__float_as_int(sxd.y) * 8 + j3];
        acc0.h[0] = __hmul2(dh, tv.h[0]); acc0.h[1] = __hmul2(dh, tv.h[1]);
        acc0.h[2] = __hmul2(dh, tv.h[2]); acc0.h[3] = __hmul2(dh, tv.h[3]);
        int2 ri = rowinfo[node];
        const int4* cs = (const int4*)(csr_src + ri.x);
        int nq = ri.y >> 2;
        int q = 0;
        for (; q + 1 < nq; q += 2) {
            int4 sA = cs[q], sB = cs[q + 1];
            float2 pa = xd[sA.x], pb = xd[sA.y], pc_ = xd[sA.z], pd = xd[sA.w];
            float2 pe = xd[sB.x], pf = xd[sB.y], pg = xd[sB.z], ph = xd[sB.w];
            H8 u0, u1, u2, u3, u4, u5, u6, u7;
            u0.f = th4[(size_t)__float_as_int(pa.y)  * 8 + j3];
            u1.f = th4[(size_t)__float_as_int(pb.y)  * 8 + j3];
            u2.f = th4[(size_t)__float_as_int(pc_.y) * 8 + j3];
            u3.f = th4[(size_t)__float_as_int(pd.y)  * 8 + j3];
            u4.f = th4[(size_t)__float_as_int(pe.y)  * 8 + j3];
            u5.f = th4[(size_t)__float_as_int(pf.y)  * 8 + j3];
            u6.f = th4[(size_t)__float_as_int(pg.y)  * 8 + j3];
            u7.f = th4[(size_t)__float_as_int(ph.y)  * 8 + j3];
            __half2 w0 = __float2half2_rn(pa.x), w1 = __float2half2_rn(pb.x);
            __half2 w2 = __float2half2_rn(pc_.x), w3 = __float2half2_rn(pd.x);
            __half2 w4 = __float2half2_rn(pe.x), w5 = __float2half2_rn(pf.x);
            __half2 w6 = __float2half2_rn(pg.x), w7 = __float2half2_rn(ph.x);
            #pragma unroll
            for (int t = 0; t < 4; ++t) {
                acc0.h[t] = __hfma2(w0, u0.h[t], acc0.h[t]);
                acc1.h[t] = __hfma2(w1, u1.h[t], acc1.h[t]);
                acc2.h[t] = __hfma2(w2, u2.h[t], acc2.h[t]);
                acc3.h[t] = __hfma2(w3, u3.h[t], acc3.h[t]);
                acc0.h[t] = __hfma2(w4, u4.h[t], acc0.h[t]);
                acc1.h[t] = __hfma2(w5, u5.h[t], acc1.h[t]);
                acc2.h[t] = __hfma2(w6, u6.h[t], acc2.h[t]);
                acc3.h[t] = __hfma2(w7, u7.h[t], acc3.h[t]);
            }
        }
        if (q < nq) {
            int4 sA = cs[q];
            float2 pa = xd[sA.x], pb = xd[sA.y], pc_ = xd[sA.z], pd = xd[sA.w];
            H8 u0, u1, u2, u3;
            u0.f = th4[(size_t)__float_as_int(pa.y)  * 8 + j3];
            u1.f = th4[(size_t)__float_as_int(pb.y)  * 8 + j3];
            u2.f = th4[(size_t)__float_as_int(pc_.y) * 8 + j3];
            u3.f = th4[(size_t)__float_as_int(pd.y)  * 8 + j3];
            __half2 w0 = __float2half2_rn(pa.x), w1 = __float2half2_rn(pb.x);
            __half2 w2 = __float2half2_rn(pc_.x), w3 = __float2half2_rn(pd.x);
            #pragma unroll
            for (int t = 0; t < 4; ++t) {
                acc0.h[t] = __hfma2(w0, u0.h[t], acc0.h[t]);
                acc1.h[t] = __hfma2(w1, u1.h[t], acc1.h[t]);
                acc2.h[t] = __hfma2(w2, u2.h[t], acc2.h[t]);
                acc3.h[t] = __hfma2(w3, u3.h[t], acc3.h[t]);
            }
        }
        #pragma unroll
        for (int t = 0; t < 4; ++t)
            acc0.h[t] = __hmul2(dh, __hadd2(__hadd2(acc0.h[t], acc1.h[t]),
                                            __hadd2(acc2.h[t], acc3.h[t])));
    }
    Hs4[node_l * 9 + j3] = acc0.f;
    __syncthreads();

    // MFMA MLP: 2 tiles of 16 rows; each wave does cols wave*16..+15, K=64.
    int wave = tid >> 6, lane = tid & 63;
    int m = lane & 15, quad = lane >> 4;
    int ncol = wave * 16 + m;
    F4H8 b0, b1;
    const float4* WT4 = (const float4*)wt;
    b0.f = WT4[ncol * 8 + quad];
    b1.f = WT4[ncol * 8 + 4 + quad];
    float bb_ = bias[ncol];
    #pragma unroll
    for (int t = 0; t < 2; ++t) {
        F4H8 a0, a1;
        a0.f = Hs4[(t * 16 + m) * 9 + quad];
        a1.f = Hs4[(t * 16 + m) * 9 + 4 + quad];
        float4_t acc = {0.f, 0.f, 0.f, 0.f};
        acc = __builtin_amdgcn_mfma_f32_16x16x32_f16(a0.h, b0.h, acc, 0, 0, 0);
        acc = __builtin_amdgcn_mfma_f32_16x16x32_f16(a1.h, b1.h, acc, 0, 0, 0);
        #pragma unroll
        for (int reg = 0; reg < 4; ++reg) {
            int row = t * 16 + quad * 4 + reg;
            int grow = row0 + row;
            if (grow < N) {
                float h = fmaxf(acc[reg] + bb_, 0.0f);
                g1h[(size_t)grow * DD + ncol] = __float2half(dvs[row] * h);
            }
        }
    }
}

// -------- layer 2 + pool: gather g1h, MFMA MLP, Wlin dot + segmented pool ---
__global__ __launch_bounds__(256, 8) void layer2_pool_kernel(
        const int2* __restrict__ rowinfo,
        const int* __restrict__ csr_src, const float2* __restrict__ xd,
        const float4* __restrict__ g1h4, const __half* __restrict__ wt,
        const float* __restrict__ bias, const int* __restrict__ batch,
        const float* __restrict__ Wlin, float* __restrict__ outacc, int N) {
    __shared__ float4 Hs4[32 * 9];       // padded stride 9
    __shared__ float lp0[128], lp1[128]; // [wave][row]
    __shared__ float p0s[32], p1s[32];
    __shared__ int   bat[32];
    int row0 = blockIdx.x * 32;
    int tid = threadIdx.x;
    int node_l = tid >> 3, j3 = tid & 7;
    int node = row0 + node_l;
    H8 acc0, acc1, acc2, acc3;
    acc0.f = make_float4(0.f, 0.f, 0.f, 0.f);
    acc1.f = acc0.f; acc2.f = acc0.f; acc3.f = acc0.f;
    if (node < N) {
        float di = xd[node].x;
        acc0.f = g1h4[(size_t)node * 8 + j3];   // self term, weight 1
        int2 ri = rowinfo[node];
        const int4* cs = (const int4*)(csr_src + ri.x);
        int nq = ri.y >> 2;
        int q = 0;
        for (; q + 1 < nq; q += 2) {
            int4 sA = cs[q], sB = cs[q + 1];
            H8 u0, u1, u2, u3, u4, u5, u6, u7;
            u0.f = g1h4[(size_t)sA.x * 8 + j3];
            u1.f = g1h4[(size_t)sA.y * 8 + j3];
            u2.f = g1h4[(size_t)sA.z * 8 + j3];
            u3.f = g1h4[(size_t)sA.w * 8 + j3];
            u4.f = g1h4[(size_t)sB.x * 8 + j3];
            u5.f = g1h4[(size_t)sB.y * 8 + j3];
            u6.f = g1h4[(size_t)sB.z * 8 + j3];
            u7.f = g1h4[(size_t)sB.w * 8 + j3];
            #pragma unroll
            for (int t = 0; t < 4; ++t) {
                acc0.h[t] = __hadd2(acc0.h[t], u0.h[t]);
                acc1.h[t] = __hadd2(acc1.h[t], u1.h[t]);
                acc2.h[t] = __hadd2(acc2.h[t], u2.h[t]);
                acc3.h[t] = __hadd2(acc3.h[t], u3.h[t]);
                acc0.h[t] = __hadd2(acc0.h[t], u4.h[t]);
                acc1.h[t] = __hadd2(acc1.h[t], u5.h[t]);
                acc2.h[t] = __hadd2(acc2.h[t], u6.h[t]);
                acc3.h[t] = __hadd2(acc3.h[t], u7.h[t]);
            }
        }
        if (q < nq) {
            int4 sA = cs[q];
            H8 u0, u1, u2, u3;
            u0.f = g1h4[(size_t)sA.x * 8 + j3];
            u1.f = g1h4[(size_t)sA.y * 8 + j3];
            u2.f = g1h4[(size_t)sA.z * 8 + j3];
            u3.f = g1h4[(size_t)sA.w * 8 + j3];
            #pragma unroll
            for (int t = 0; t < 4; ++t) {
                acc0.h[t] = __hadd2(acc0.h[t], u0.h[t]);
                acc1.h[t] = __hadd2(acc1.h[t], u1.h[t]);
                acc2.h[t] = __hadd2(acc2.h[t], u2.h[t]);
                acc3.h[t] = __hadd2(acc3.h[t], u3.h[t]);
            }
        }
        __half2 dih = __float2half2_rn(di);
        #pragma unroll
        for (int t = 0; t < 4; ++t)
            acc0.h[t] = __hmul2(dih, __hadd2(__hadd2(acc0.h[t], acc1.h[t]),
                                             __hadd2(acc2.h[t], acc3.h[t])));
    }
    Hs4[node_l * 9 + j3] = acc0.f;
    __syncthreads();

    int wave = tid >> 6, lane = tid & 63;
    int m = lane & 15, quad = lane >> 4;
    int ncol = wave * 16 + m;
    F4H8 b0, b1;
    const float4* WT4 = (const float4*)wt;
    b0.f = WT4[ncol * 8 + quad];
    b1.f = WT4[ncol * 8 + 4 + quad];
    float bb_  = bias[ncol];
    float wl0 = Wlin[ncol * 2 + 0];
    float wl1 = Wlin[ncol * 2 + 1];
    #pragma unroll
    for (int t = 0; t < 2; ++t) {
        F4H8 a0, a1;
        a0.f = Hs4[(t * 16 + m) * 9 + quad];
        a1.f = Hs4[(t * 16 + m) * 9 + 4 + quad];
        float4_t acc = {0.f, 0.f, 0.f, 0.f};
        acc = __builtin_amdgcn_mfma_f32_16x16x32_f16(a0.h, b0.h, acc, 0, 0, 0);
        acc = __builtin_amdgcn_mfma_f32_16x16x32_f16(a1.h, b1.h, acc, 0, 0, 0);
        #pragma unroll
        for (int reg = 0; reg < 4; ++reg) {
            int row = t * 16 + quad * 4 + reg;
            int grow = row0 + row;
            float h = (grow < N) ? fmaxf(acc[reg] + bb_, 0.0f) : 0.0f;
            float p0 = h * wl0;
            float p1 = h * wl1;
            #pragma unroll
            for (int off = 8; off >= 1; off >>= 1) {   // sum over 16 cols (m)
                p0 += __shfl_xor(p0, off);
                p1 += __shfl_xor(p1, off);
            }
            if (m == 0) {
                lp0[wave * 32 + row] = p0;
                lp1[wave * 32 + row] = p1;
            }
        }
    }
    __syncthreads();
    if (tid < 32) {
        int grow = row0 + tid;
        p0s[tid] = lp0[tid] + lp0[32 + tid] + lp0[64 + tid] + lp0[96 + tid];
        p1s[tid] = lp1[tid] + lp1[32 + tid] + lp1[64 + tid] + lp1[96 + tid];
        bat[tid] = (grow < N) ? batch[grow] : -1;
    }
    __syncthreads();
    if (tid < 32) {
        int bg = bat[tid];
        bool head = (bg >= 0) && (tid == 0 || bat[tid - 1] != bg);
        if (head) {
            float s0 = 0.f, s1 = 0.f;
            for (int k = tid; k < 32 && bat[k] == bg; ++k) {
                s0 += p0s[k];
                s1 += p1s[k];
            }
            atomAddF(&outacc[bg * 2 + 0], s0);
            atomAddF(&outacc[bg * 2 + 1], s1);
        }
    }
}

// counts via binary search on sorted batch; then divide + blin
__global__ void final_kernel(const float* __restrict__ outacc,
                             const int* __restrict__ batch,
                             const float* __restrict__ blin,
                             float* __restrict__ out, int G, int N) {
    int t = blockIdx.x * blockDim.x + threadIdx.x;
    if (t >= G * 2) return;
    int g = t >> 1, c = t & 1;
    int lo = 0, hi = N;
    while (lo < hi) { int m = (lo + hi) >> 1; if (batch[m] < g) lo = m + 1; else hi = m; }
    int lo2 = lo, hi2 = N;
    while (lo2 < hi2) { int m = (lo2 + hi2) >> 1; if (batch[m] < g + 1) lo2 = m + 1; else hi2 = m; }
    float cnt = (float)(lo2 - lo);
    out[t] = outacc[t] / fmaxf(cnt, 1.0f) + blin[c];
}

extern "C" void kernel_launch(void* const* d_in, const int* in_sizes, int n_in,
                              void* d_out, int out_size, void* d_ws, size_t ws_size,
                              hipStream_t stream) {
    const int*   x      = (const int*)d_in[0];
    const int*   ei     = (const int*)d_in[1];   // [2,E] row-major
    const int*   batch  = (const int*)d_in[3];
    const float* table  = (const float*)d_in[4];
    const float* W1     = (const float*)d_in[5];
    const float* b1     = (const float*)d_in[6];
    const float* W2     = (const float*)d_in[7];
    const float* b2     = (const float*)d_in[8];
    const float* Wlin   = (const float*)d_in[9];
    const float* blin   = (const float*)d_in[10];
    float* out = (float*)d_out;

    const int N = in_sizes[0];
    const int E = in_sizes[2];          // edge_type count == E
    const int G = out_size / 2;
    const int TBL = in_sizes[4];        // VOCAB*DD floats

    const int* src = ei;
    const int* dst = ei + E;

    const int K = (N + BKT - 1) / BKT;  // buckets
    const int M = NBLK * MAXK;          // (block, bucket) cells
    const int CH = (E + NBLK - 1) / NBLK;
    const int CSRSZ = E + SLACK * K + 64;

    // workspace layout (keep 16-B alignment for b128 reads)
    __half* g1h     = (__half*)d_ws;                      // (N+1)*64 halves
    __half* th      = g1h + (size_t)(N + 1) * DD;         // TBL halves
    __half* w1t     = th + TBL;                           // 4096 halves
    __half* w2t     = w1t + DD * DD;                      // 4096 halves
    int*    pairbuf = (int*)(w2t + DD * DD);              // E ints
    int*    csr_src = pairbuf + E;                        // CSRSZ ints
    int2*   rowinfo = (int2*)(csr_src + CSRSZ);           // N int2
    float2* xd      = (float2*)(rowinfo + N);             // N+1 float2
    float*  outacc  = (float*)(xd + N + 1);               // 2G (zeroed in totals)
    int*    bb      = (int*)(outacc + 2 * G);             // K+1
    int*    bts     = bb + K + 1;                         // K
    int*    hist    = bts + K;                            // M
    int*    cur     = hist + M;                           // M

    const int BT = 256;

    // partition: per-chunk histogram -> wave-totals(+outacc zero) -> bucket
    //            scan -> per-bucket block scan -> append -> CSR sort
    bin_count_kernel<<<NBLK, BTE, 0, stream>>>(dst, E, CH, hist, K,
                                               (const float2*)table,
                                               (__half2*)th, TBL / 2,
                                               W1, W2, w1t, w2t);
    totals_kernel<<<(K * 64 + BT - 1) / BT, BT, 0, stream>>>(hist, bts, outacc,
                                                             K, 2 * G);
    scan_bb_kernel<<<1, BT, 0, stream>>>(bts, bb, K, E);
    scanB_kernel<<<(K * 64 + BT - 1) / BT, BT, 0, stream>>>(hist, bb, cur, K);
    fill_kernel<<<NBLK, BTE, 0, stream>>>(src, dst, E, CH, cur, pairbuf, K);
    build_csr_kernel<<<K, BT, 0, stream>>>(pairbuf, bb, x, rowinfo, xd,
                                           csr_src, g1h, N);

    // layer 1 (embed+agg+MFMA-MLP+relu fused; writes g1h = fp16(dinv*h1))
    int gRow = (N + 31) / 32;
    layer1_kernel<<<gRow, BT, 0, stream>>>(rowinfo, csr_src, xd,
                                           (const float4*)th, w1t, b1, g1h, N);
    // layer 2 (agg+MFMA-MLP+relu+pool fused)
    layer2_pool_kernel<<<gRow, BT, 0, stream>>>(rowinfo, csr_src, xd,
                                                (const float4*)g1h, w2t, b2,
                                                batch, Wlin, outacc, N);
    // final
    final_kernel<<<(G * 2 + BT - 1) / BT, BT, 0, stream>>>(outacc, batch, blin,
                                                           out, G, N);
}